// Round 14
// baseline (518.951 us; speedup 1.0000x reference)
//
#include <hip/hip_runtime.h>

static constexpr int TPB = 256;

// ---- bf16 helpers ----
__device__ __forceinline__ unsigned bf16rne(float x) {
    unsigned u = __float_as_uint(x);
    return (u + 0x7fffu + ((u >> 16) & 1u)) >> 16;
}
__device__ __forceinline__ unsigned pack2(float a, float b) {
    return bf16rne(a) | (bf16rne(b) << 16);
}
__device__ __forceinline__ float dotu(unsigned a, unsigned b) {
    float alo = __uint_as_float(a << 16), ahi = __uint_as_float(a & 0xffff0000u);
    float blo = __uint_as_float(b << 16), bhi = __uint_as_float(b & 0xffff0000u);
    return alo * blo + ahi * bhi;
}
__device__ __forceinline__ float dot4(float4 a, float4 b) {
    return a.x * b.x + a.y * b.y + a.z * b.z + a.w * b.w;
}

// ---- fixed-point packed rs/deg: deg in bits [44..63], rs*2^20 in bits [0..43] ----
__device__ __forceinline__ unsigned long long rsd_pack(float s) {
    return (1ull << 44) | (unsigned long long)__float2uint_rn(s * 1048576.0f);
}
__device__ __forceinline__ float rsd_rs(unsigned long long v) {
    return (float)(v & 0xFFFFFFFFFFFull) * (1.0f / 1048576.0f);
}
__device__ __forceinline__ float rsd_deg(unsigned long long v) {
    return (float)(unsigned)(v >> 44);
}

// ==================== col counting sort -> col-CSR (atomic-free scatter) ====================
__global__ void hist_kernel(const int* __restrict__ col, int* __restrict__ cnt,
                            int* __restrict__ rank, int er) {
    int e = blockIdx.x * TPB + threadIdx.x;
    if (e >= er) return;
    rank[e] = atomicAdd(&cnt[col[e]], 1);
}

__global__ void scan1_kernel(const int* __restrict__ cnt, int* __restrict__ base,
                             int* __restrict__ bsum, int n) {
    __shared__ int s[TPB];
    int g = blockIdx.x * TPB + threadIdx.x;
    int v = (g < n) ? cnt[g] : 0;
    s[threadIdx.x] = v;
    __syncthreads();
    for (int off = 1; off < TPB; off <<= 1) {
        int t = (threadIdx.x >= off) ? s[threadIdx.x - off] : 0;
        __syncthreads();
        s[threadIdx.x] += t;
        __syncthreads();
    }
    if (g < n) base[g] = s[threadIdx.x] - v;
    if (threadIdx.x == TPB - 1) bsum[blockIdx.x] = s[threadIdx.x];
}

__global__ void scan2_kernel(int* __restrict__ bsum, int nb) {
    __shared__ int s[TPB];
    int v = (threadIdx.x < nb) ? bsum[threadIdx.x] : 0;
    s[threadIdx.x] = v;
    __syncthreads();
    for (int off = 1; off < TPB; off <<= 1) {
        int t = (threadIdx.x >= off) ? s[threadIdx.x - off] : 0;
        __syncthreads();
        s[threadIdx.x] += t;
        __syncthreads();
    }
    if (threadIdx.x < nb) bsum[threadIdx.x] = s[threadIdx.x] - v;
}

// base[g] -> global start; ptr[g] -> global END (= start + cnt)
__global__ void scan3_kernel(int* __restrict__ base, int* __restrict__ ptr,
                             const int* __restrict__ bsum, const int* __restrict__ cnt, int n) {
    int g = blockIdx.x * TPB + threadIdx.x;
    if (g >= n) return;
    int b = base[g] + bsum[g >> 8];
    base[g] = b;
    ptr[g] = b + cnt[g];
}

// atomic-free scatter: one 4B scattered store per edge
__global__ void scatter_kernel(const int* __restrict__ row, const int* __restrict__ col,
                               const int* __restrict__ base, const int* __restrict__ rank,
                               int* __restrict__ rowp, int er) {
    int e = blockIdx.x * TPB + threadIdx.x;
    if (e >= er) return;
    rowp[base[col[e]] + rank[e]] = row[e];
}

// coalesced segmented fill of colp from the CSR
__global__ void colfill_kernel(const int* __restrict__ base, const int* __restrict__ endp,
                               int* __restrict__ colp, int n) {
    int gid = blockIdx.x * TPB + threadIdx.x;
    int c = gid >> 2;
    int l = gid & 3;
    if (c >= n) return;
    int e_end = endp[c];
    for (int i = base[c] + l; i < e_end; i += 4) colp[i] = c;
}

// ==================== layer-0: inv norm + normalized bf16 copy (16 lanes/node) ====================
__global__ void norm_kernel(const float* __restrict__ feat, float* __restrict__ inv,
                            unsigned* __restrict__ xb, int n) {
    int gid = blockIdx.x * TPB + threadIdx.x;
    int node = gid >> 4;
    int lane = gid & 15;
    if (node >= n) return;
    const float4* fr = (const float4*)(feat + (size_t)node * 128);
    float4 v0 = fr[lane * 2], v1 = fr[lane * 2 + 1];
    float ss = dot4(v0, v0) + dot4(v1, v1);
#pragma unroll
    for (int off = 8; off > 0; off >>= 1) ss += __shfl_xor(ss, off);
    float iv = (ss > 0.f) ? rsqrtf(ss) : 1.0f;
    if (lane == 0) inv[node] = iv;
    uint4 q;
    q.x = pack2(v0.x * iv, v0.y * iv);
    q.y = pack2(v0.z * iv, v0.w * iv);
    q.z = pack2(v1.x * iv, v1.y * iv);
    q.w = pack2(v1.z * iv, v1.w * iv);
    ((uint4*)xb)[(size_t)node * 16 + lane] = q;
}

// ==================== bf16-screened cosine sim, F=128 (16 lanes/edge, 2 edges/thread) ====================
__global__ void simbf_kernel(const unsigned* __restrict__ xb, const float* __restrict__ feat,
                             const float* __restrict__ inv,
                             const int* __restrict__ rowp, const int* __restrict__ colp,
                             float* __restrict__ sim, unsigned long long* __restrict__ rsd,
                             long long ne) {
    constexpr float MARGIN = 0.02f;
    long long half = (ne + 1) >> 1;
    long long gid = (long long)blockIdx.x * TPB + threadIdx.x;
    long long slot = gid >> 4;
    int lane = (int)(gid & 15);
    if (slot >= half) return;
    long long e0 = slot;
    long long e1 = slot + half;
    bool has1 = (e1 < ne);
    if (!has1) e1 = e0;
    int r0 = rowp[e0], c0 = colp[e0];
    int r1 = rowp[e1], c1 = colp[e1];
    const uint4* X = (const uint4*)xb;
    uint4 a0 = X[(size_t)r0 * 16 + lane];
    uint4 b0 = X[(size_t)c0 * 16 + lane];
    uint4 a1 = X[(size_t)r1 * 16 + lane];
    uint4 b1 = X[(size_t)c1 * 16 + lane];
    float s0 = dotu(a0.x, b0.x) + dotu(a0.y, b0.y) + dotu(a0.z, b0.z) + dotu(a0.w, b0.w);
    float s1 = dotu(a1.x, b1.x) + dotu(a1.y, b1.y) + dotu(a1.z, b1.z) + dotu(a1.w, b1.w);
#pragma unroll
    for (int off = 8; off > 0; off >>= 1) {
        s0 += __shfl_xor(s0, off);
        s1 += __shfl_xor(s1, off);
    }
    if (fabsf(s0 - 0.5f) < MARGIN && r0 != c0) {
        const float4* fa = (const float4*)(feat + (size_t)r0 * 128);
        const float4* fb = (const float4*)(feat + (size_t)c0 * 128);
        float d = dot4(fa[lane * 2], fb[lane * 2]) + dot4(fa[lane * 2 + 1], fb[lane * 2 + 1]);
#pragma unroll
        for (int off = 8; off > 0; off >>= 1) d += __shfl_xor(d, off);
        s0 = d * inv[r0] * inv[c0];
    }
    if (has1 && fabsf(s1 - 0.5f) < MARGIN && r1 != c1) {
        const float4* fa = (const float4*)(feat + (size_t)r1 * 128);
        const float4* fb = (const float4*)(feat + (size_t)c1 * 128);
        float d = dot4(fa[lane * 2], fb[lane * 2]) + dot4(fa[lane * 2 + 1], fb[lane * 2 + 1]);
#pragma unroll
        for (int off = 8; off > 0; off >>= 1) d += __shfl_xor(d, off);
        s1 = d * inv[r1] * inv[c1];
    }
    if (lane == 0) {
        if (s0 < 0.5f || r0 == c0) s0 = 0.f;
        sim[e0] = s0;
        if (s0 > 0.f) atomicAdd(&rsd[r0], rsd_pack(s0));
        if (has1) {
            if (s1 < 0.5f || r1 == c1) s1 = 0.f;
            sim[e1] = s1;
            if (s1 > 0.f) atomicAdd(&rsd[r1], rsd_pack(s1));
        }
    }
}

// ==================== fp32 cosine sim for F=16: one edge/thread, one packed atomic ====================
__global__ void sim16_kernel(const float* __restrict__ feat, const float* __restrict__ inv,
                             const int* __restrict__ rowp, const int* __restrict__ colp,
                             float* __restrict__ sim, unsigned long long* __restrict__ rsd,
                             long long ne) {
    long long e = (long long)blockIdx.x * TPB + threadIdx.x;
    if (e >= ne) return;
    int r = rowp[e], c = colp[e];
    const float4* fa = (const float4*)(feat + (size_t)r * 16);
    const float4* fb = (const float4*)(feat + (size_t)c * 16);
    float4 a0 = fa[0], a1 = fa[1], a2 = fa[2], a3 = fa[3];
    float4 b0 = fb[0], b1 = fb[1], b2 = fb[2], b3 = fb[3];
    float s = dot4(a0, b0) + dot4(a1, b1) + dot4(a2, b2) + dot4(a3, b3);
    s *= inv[r] * inv[c];
    if (s < 0.5f || r == c) s = 0.f;
    sim[e] = s;
    if (s > 0.f) atomicAdd(&rsd[r], rsd_pack(s));
}

// ==================== col-segmented: w=exp(sim/rs[row]); deg2[c]=ws_self+Σw ====================
__global__ void wdeg2_kernel(float* __restrict__ ew, const unsigned long long* __restrict__ rsd,
                             const int* __restrict__ rowp,
                             const int* __restrict__ base, const int* __restrict__ endp,
                             float* __restrict__ deg2, float* __restrict__ ws_self, int n) {
    int gid = blockIdx.x * TPB + threadIdx.x;
    int c = gid >> 2;
    int l = gid & 3;
    if (c >= n) return;
    int s = base[c], e_end = endp[c];
    float sum = 0.f;
    for (int e = s + l; e < e_end; e += 4) {
        float sv = ew[e];
        if (sv > 0.f) {
            float w = __expf(sv / rsd_rs(rsd[rowp[e]]));
            ew[e] = w;
            sum += w;
        }
    }
    sum += __shfl_xor(sum, 1, 4);
    sum += __shfl_xor(sum, 2, 4);
    if (l == 0) {
        float wsf = __expf(1.0f / (rsd_deg(rsd[c]) + 1.0f));
        ws_self[c] = wsf;
        deg2[c] = wsf + sum;
    }
}

// ==================== dense h = feat @ W, 128x128: BM=128, 8x8 register tile ====================
// 256 threads: j8 = tid&15 (cols j8*4 and 64+j8*4), sub = tid>>4 (nodes sub + s*16, s=0..7).
// Per 4-k chunk: 16 ds_read_b128 per 256 FMA inst -> LDS-cyc/FMA halved vs 4x4 tile.
// No prefetch registers (R9 lesson: spill), cap 3 waves/SIMD.
__global__ __launch_bounds__(256, 3) void gemm128_kernel(const float* __restrict__ feat,
                                                         const float* __restrict__ W,
                                                         float* __restrict__ out, int n) {
    constexpr int FIN = 128, FOUT = 128, BM = 128, BK = 32, FPAD = 36;
    __shared__ float Wl[BK * FOUT];        // 16 KB
    __shared__ float Fl[BM * FPAD];        // 18 KB
    int tid = threadIdx.x;
    int base = blockIdx.x * BM;
    int j8 = tid & 15;
    int sub = tid >> 4;
    float4 accL[8], accH[8];
#pragma unroll
    for (int s = 0; s < 8; ++s) {
        accL[s] = make_float4(0.f, 0.f, 0.f, 0.f);
        accH[s] = make_float4(0.f, 0.f, 0.f, 0.f);
    }

    for (int t = 0; t < FIN / BK; ++t) {
        int k0 = t * BK;
        if (t > 0) __syncthreads();
#pragma unroll
        for (int i = 0; i < 4; ++i) {   // stage W tile: 1024 float4
            int idx = tid + 256 * i;
            int r = idx >> 5, c4 = idx & 31;
            *(float4*)&Wl[r * FOUT + c4 * 4] =
                *(const float4*)(W + (size_t)(k0 + r) * FOUT + c4 * 4);
        }
#pragma unroll
        for (int i = 0; i < 4; ++i) {   // stage F tile: 1024 float4
            int idx = tid + 256 * i;
            int r = idx >> 3, c4 = idx & 7;
            int node = base + r;
            float4 v = make_float4(0.f, 0.f, 0.f, 0.f);
            if (node < n) v = *(const float4*)(feat + (size_t)node * FIN + k0 + c4 * 4);
            *(float4*)&Fl[r * FPAD + c4 * 4] = v;
        }
        __syncthreads();
#pragma unroll
        for (int k = 0; k < BK; k += 4) {
            float4 wl[4], wh[4];
#pragma unroll
            for (int kk = 0; kk < 4; ++kk) {
                wl[kk] = *(const float4*)&Wl[(k + kk) * FOUT + j8 * 4];
                wh[kk] = *(const float4*)&Wl[(k + kk) * FOUT + 64 + j8 * 4];
            }
#pragma unroll
            for (int s = 0; s < 8; ++s) {
                float4 f = *(const float4*)&Fl[(sub + s * 16) * FPAD + k];
                accL[s].x += f.x * wl[0].x + f.y * wl[1].x + f.z * wl[2].x + f.w * wl[3].x;
                accL[s].y += f.x * wl[0].y + f.y * wl[1].y + f.z * wl[2].y + f.w * wl[3].y;
                accL[s].z += f.x * wl[0].z + f.y * wl[1].z + f.z * wl[2].z + f.w * wl[3].z;
                accL[s].w += f.x * wl[0].w + f.y * wl[1].w + f.z * wl[2].w + f.w * wl[3].w;
                accH[s].x += f.x * wh[0].x + f.y * wh[1].x + f.z * wh[2].x + f.w * wh[3].x;
                accH[s].y += f.x * wh[0].y + f.y * wh[1].y + f.z * wh[2].y + f.w * wh[3].y;
                accH[s].z += f.x * wh[0].z + f.y * wh[1].z + f.z * wh[2].z + f.w * wh[3].z;
                accH[s].w += f.x * wh[0].w + f.y * wh[1].w + f.z * wh[2].w + f.w * wh[3].w;
            }
        }
    }
#pragma unroll
    for (int s = 0; s < 8; ++s) {
        int node = base + sub + s * 16;
        if (node < n) {
            *(float4*)(out + (size_t)node * FOUT + j8 * 4) = accL[s];
            *(float4*)(out + (size_t)node * FOUT + 64 + j8 * 4) = accH[s];
        }
    }
}

// ==================== h = feat @ W for FOUT=16 (4 lanes per node, float4) ====================
template<int FIN>
__global__ void matmulS_kernel(const float* __restrict__ feat, const float* __restrict__ W,
                               float* __restrict__ out, int n) {
    __shared__ float4 Wl[FIN * 4];
    for (int i = threadIdx.x; i < FIN * 4; i += TPB) Wl[i] = ((const float4*)W)[i];
    __syncthreads();
    int gid = blockIdx.x * TPB + threadIdx.x;
    int node = gid >> 2;
    int j4 = gid & 3;
    if (node >= n) return;
    const float4* fr = (const float4*)(feat + (size_t)node * FIN);
    float4 acc = make_float4(0.f, 0.f, 0.f, 0.f);
#pragma unroll
    for (int k4 = 0; k4 < FIN / 4; ++k4) {
        float4 f = fr[k4];
        float4 w0 = Wl[(4 * k4 + 0) * 4 + j4];
        float4 w1 = Wl[(4 * k4 + 1) * 4 + j4];
        float4 w2 = Wl[(4 * k4 + 2) * 4 + j4];
        float4 w3 = Wl[(4 * k4 + 3) * 4 + j4];
        acc.x += f.x * w0.x + f.y * w1.x + f.z * w2.x + f.w * w3.x;
        acc.y += f.x * w0.y + f.y * w1.y + f.z * w2.y + f.w * w3.y;
        acc.z += f.x * w0.z + f.y * w1.z + f.z * w2.z + f.w * w3.z;
        acc.w += f.x * w0.w + f.y * w1.w + f.z * w2.w + f.w * w3.w;
    }
    *((float4*)(out + (size_t)node * 16) + j4) = acc;
}

// ==================== fused segmented aggregate + finalize, F=128 (32 lanes/col) ====================
template<bool RELU>
__global__ void aggfin128_kernel(const float* __restrict__ h, const float* __restrict__ ew,
                                 const float* __restrict__ deg2, const int* __restrict__ rowp,
                                 const int* __restrict__ base, const int* __restrict__ endp,
                                 const float* __restrict__ ws_self, const float* __restrict__ b,
                                 float* __restrict__ outb, float* __restrict__ inv,
                                 unsigned* __restrict__ xb, int n) {
    int gid = blockIdx.x * TPB + threadIdx.x;
    int c = gid >> 5;
    int j4 = gid & 31;
    if (c >= n) return;
    int s = base[c], e_end = endp[c];
    float d2c = deg2[c];
    float dc = rsqrtf(d2c);
    float4 acc = make_float4(0.f, 0.f, 0.f, 0.f);
    for (int e = s; e < e_end; ++e) {
        float we = ew[e];
        if (we == 0.f) continue;
        int r = rowp[e];
        float nw = rsqrtf(deg2[r]) * we * dc;
        float4 hv = *((const float4*)(h + (size_t)r * 128) + j4);
        acc.x += nw * hv.x; acc.y += nw * hv.y; acc.z += nw * hv.z; acc.w += nw * hv.w;
    }
    float nws = ws_self[c] / d2c;
    float4 hv = *((const float4*)(h + (size_t)c * 128) + j4);
    float4 bv = ((const float4*)b)[j4];
    float4 o;
    o.x = acc.x + nws * hv.x + bv.x;
    o.y = acc.y + nws * hv.y + bv.y;
    o.z = acc.z + nws * hv.z + bv.z;
    o.w = acc.w + nws * hv.w + bv.w;
    if (RELU) {
        o.x = fmaxf(o.x, 0.f); o.y = fmaxf(o.y, 0.f);
        o.z = fmaxf(o.z, 0.f); o.w = fmaxf(o.w, 0.f);
    }
    *((float4*)(outb + (size_t)c * 128) + j4) = o;
    float ss = o.x * o.x + o.y * o.y + o.z * o.z + o.w * o.w;
#pragma unroll
    for (int off = 16; off > 0; off >>= 1)
        ss += __shfl_xor(ss, off, 32);
    float iv = (ss > 0.f) ? rsqrtf(ss) : 1.0f;
    if (j4 == 0) inv[c] = iv;
    uint2 p;
    p.x = pack2(o.x * iv, o.y * iv);
    p.y = pack2(o.z * iv, o.w * iv);
    ((uint2*)xb)[(size_t)c * 32 + j4] = p;
}

// ==================== fused segmented aggregate + finalize, F=16 (4 lanes/col) ====================
template<bool RELU, bool LOGSM, bool WINV>
__global__ void aggfin16_kernel(const float* __restrict__ h, const float* __restrict__ ew,
                                const float* __restrict__ deg2, const int* __restrict__ rowp,
                                const int* __restrict__ base, const int* __restrict__ endp,
                                const float* __restrict__ ws_self, const float* __restrict__ b,
                                float* __restrict__ out, float* __restrict__ inv, int n) {
    int gid = blockIdx.x * TPB + threadIdx.x;
    int c = gid >> 2;
    int l = gid & 3;
    if (c >= n) return;
    int s = base[c], e_end = endp[c];
    float d2c = deg2[c];
    float dc = rsqrtf(d2c);
    float4 acc = make_float4(0.f, 0.f, 0.f, 0.f);
    for (int e = s; e < e_end; ++e) {
        float we = ew[e];
        if (we == 0.f) continue;
        int r = rowp[e];
        float nw = rsqrtf(deg2[r]) * we * dc;
        float4 hv = *((const float4*)(h + (size_t)r * 16) + l);
        acc.x += nw * hv.x; acc.y += nw * hv.y; acc.z += nw * hv.z; acc.w += nw * hv.w;
    }
    float nws = ws_self[c] / d2c;
    float4 hv = *((const float4*)(h + (size_t)c * 16) + l);
    float4 bv = ((const float4*)b)[l];
    float4 v;
    v.x = acc.x + nws * hv.x + bv.x;
    v.y = acc.y + nws * hv.y + bv.y;
    v.z = acc.z + nws * hv.z + bv.z;
    v.w = acc.w + nws * hv.w + bv.w;
    if (RELU) {
        v.x = fmaxf(v.x, 0.f); v.y = fmaxf(v.y, 0.f);
        v.z = fmaxf(v.z, 0.f); v.w = fmaxf(v.w, 0.f);
    }
    if (WINV) {
        float ss = v.x * v.x + v.y * v.y + v.z * v.z + v.w * v.w;
        ss += __shfl_xor(ss, 1, 4);
        ss += __shfl_xor(ss, 2, 4);
        if (l == 0) inv[c] = (ss > 0.f) ? rsqrtf(ss) : 1.0f;
    }
    if (LOGSM) {
        float m = fmaxf(fmaxf(v.x, v.y), fmaxf(v.z, v.w));
        m = fmaxf(m, __shfl_xor(m, 1, 4));
        m = fmaxf(m, __shfl_xor(m, 2, 4));
        float sm = expf(v.x - m) + expf(v.y - m) + expf(v.z - m) + expf(v.w - m);
        sm += __shfl_xor(sm, 1, 4);
        sm += __shfl_xor(sm, 2, 4);
        float ls = m + logf(sm);
        v.x -= ls; v.y -= ls; v.z -= ls; v.w -= ls;
    }
    *((float4*)(out + (size_t)c * 16) + l) = v;
}

extern "C" void kernel_launch(void* const* d_in, const int* in_sizes, int n_in,
                              void* d_out, int out_size, void* d_ws, size_t ws_size,
                              hipStream_t stream) {
    const float* x  = (const float*)d_in[0];
    const int*   row = (const int*)d_in[1];
    const int*   col = (const int*)d_in[2];
    const float* W0 = (const float*)d_in[3];
    const float* b0 = (const float*)d_in[4];
    const float* W1 = (const float*)d_in[5];
    const float* b1 = (const float*)d_in[6];
    const float* W2 = (const float*)d_in[7];
    const float* b2 = (const float*)d_in[8];

    const int NFEAT = 128, NHID = 128;
    int N = in_sizes[0] / NFEAT;            // 50000
    long long E = in_sizes[1];              // 850000 (tail N are self-loops)
    long long Er = E - N;                   // 800000 random edges
    int er = (int)Er;

    float* ws = (float*)d_ws;
    float* A       = ws;                          // [N,128] h
    float* B       = A + (size_t)N * NHID;        // [N,128] feat buffer
    float* ew      = B + (size_t)N * NHID;        // [Er] sim -> w (col-sorted order)
    unsigned long long* rsd = (unsigned long long*)(ew + Er);   // [N] packed rs|deg
    float* inv     = (float*)(rsd + N);           // [N]
    float* deg2    = inv + N;                     // [N]
    float* ws_self = deg2 + N;                    // [N]
    int* cnt    = (int*)(ws_self + N);            // [N]
    int* base   = cnt + N;                        // [N] col-CSR starts
    int* ptr    = base + N;                       // [N] col-CSR ends
    int* bsum   = ptr + N;                        // [256]
    int* rank   = bsum + 256;                     // [Er] within-col rank
    int* rowp   = rank + Er;                      // [Er]
    int* colp   = rowp + Er;                      // [Er]
    unsigned* xb = (unsigned*)(colp + Er);        // [N*64] bf16x2 packed
    float* out  = (float*)d_out;                  // [N,16]

    int nb = (N + TPB - 1) / TPB;
    unsigned egrid = (unsigned)((er + TPB - 1) / TPB);
    unsigned n4grid = (unsigned)(((long long)N * 4 + TPB - 1) / TPB);

    // ---- col sort -> col-CSR; scatter has NO atomics (rank precomputed in hist) ----
    hipMemsetAsync(cnt, 0, sizeof(int) * (size_t)N, stream);
    hist_kernel<<<egrid, TPB, 0, stream>>>(col, cnt, rank, er);
    scan1_kernel<<<nb, TPB, 0, stream>>>(cnt, base, bsum, N);
    scan2_kernel<<<1, TPB, 0, stream>>>(bsum, nb);
    scan3_kernel<<<nb, TPB, 0, stream>>>(base, ptr, bsum, cnt, N);
    scatter_kernel<<<egrid, TPB, 0, stream>>>(row, col, base, rank, rowp, er);
    colfill_kernel<<<n4grid, TPB, 0, stream>>>(base, ptr, colp, N);

    // layer-0 norms + bf16 copy
    norm_kernel<<<(unsigned)(((long long)N * 16 + TPB - 1) / TPB), TPB, 0, stream>>>(x, inv, xb, N);

    long long half = (Er + 1) >> 1;
    unsigned simgrid = (unsigned)((half * 16 + TPB - 1) / TPB);

    // ---------------- layer 0: x[N,128] -> B[N,128], relu ----------------
    hipMemsetAsync(rsd, 0, sizeof(unsigned long long) * (size_t)N, stream);
    simbf_kernel<<<simgrid, TPB, 0, stream>>>(xb, x, inv, rowp, colp, ew, rsd, Er);
    wdeg2_kernel<<<n4grid, TPB, 0, stream>>>(ew, rsd, rowp, base, ptr, deg2, ws_self, N);
    gemm128_kernel<<<(unsigned)((N + 127) / 128), 256, 0, stream>>>(x, W0, A, N);
    aggfin128_kernel<true><<<(unsigned)(((long long)N * 32 + TPB - 1) / TPB), TPB, 0, stream>>>(
        A, ew, deg2, rowp, base, ptr, ws_self, b0, B, inv, xb, N);

    // ---------------- layer 1: B[N,128] -> B[N,16], relu ----------------
    hipMemsetAsync(rsd, 0, sizeof(unsigned long long) * (size_t)N, stream);
    simbf_kernel<<<simgrid, TPB, 0, stream>>>(xb, B, inv, rowp, colp, ew, rsd, Er);
    wdeg2_kernel<<<n4grid, TPB, 0, stream>>>(ew, rsd, rowp, base, ptr, deg2, ws_self, N);
    matmulS_kernel<128><<<n4grid, TPB, 0, stream>>>(B, W1, A, N);
    aggfin16_kernel<true, false, true><<<n4grid, TPB, 0, stream>>>(
        A, ew, deg2, rowp, base, ptr, ws_self, b1, B, inv, N);

    // ---------------- layer 2: B[N,16] -> out[N,16], log_softmax ----------------
    hipMemsetAsync(rsd, 0, sizeof(unsigned long long) * (size_t)N, stream);
    sim16_kernel<<<egrid, TPB, 0, stream>>>(B, inv, rowp, colp, ew, rsd, Er);
    wdeg2_kernel<<<n4grid, TPB, 0, stream>>>(ew, rsd, rowp, base, ptr, deg2, ws_self, N);
    matmulS_kernel<16><<<n4grid, TPB, 0, stream>>>(B, W2, A, N);
    aggfin16_kernel<false, true, false><<<n4grid, TPB, 0, stream>>>(
        A, ew, deg2, rowp, base, ptr, ws_self, b2, out, inv, N);
}

// Round 15
// 329.470 us; speedup vs baseline: 1.5751x; 1.5751x over previous
//
#include <hip/hip_runtime.h>

static constexpr int TPB = 256;

// ---- bf16 helpers ----
__device__ __forceinline__ unsigned bf16rne(float x) {
    unsigned u = __float_as_uint(x);
    return (u + 0x7fffu + ((u >> 16) & 1u)) >> 16;
}
__device__ __forceinline__ unsigned pack2(float a, float b) {
    return bf16rne(a) | (bf16rne(b) << 16);
}
__device__ __forceinline__ float dotu(unsigned a, unsigned b) {
    float alo = __uint_as_float(a << 16), ahi = __uint_as_float(a & 0xffff0000u);
    float blo = __uint_as_float(b << 16), bhi = __uint_as_float(b & 0xffff0000u);
    return alo * blo + ahi * bhi;
}
__device__ __forceinline__ float dot4(float4 a, float4 b) {
    return a.x * b.x + a.y * b.y + a.z * b.z + a.w * b.w;
}

// ---- fixed-point packed rs/deg: deg in bits [44..63], rs*2^20 in bits [0..43] ----
__device__ __forceinline__ unsigned long long rsd_pack(float s) {
    return (1ull << 44) | (unsigned long long)__float2uint_rn(s * 1048576.0f);
}
__device__ __forceinline__ float rsd_rs(unsigned long long v) {
    return (float)(v & 0xFFFFFFFFFFFull) * (1.0f / 1048576.0f);
}
__device__ __forceinline__ float rsd_deg(unsigned long long v) {
    return (float)(unsigned)(v >> 44);
}

// ==================== col counting sort -> col-CSR (atomic-free scatter) ====================
__global__ void hist_kernel(const int* __restrict__ col, int* __restrict__ cnt,
                            int* __restrict__ rank, int er) {
    int e = blockIdx.x * TPB + threadIdx.x;
    if (e >= er) return;
    rank[e] = atomicAdd(&cnt[col[e]], 1);
}

__global__ void scan1_kernel(const int* __restrict__ cnt, int* __restrict__ base,
                             int* __restrict__ bsum, int n) {
    __shared__ int s[TPB];
    int g = blockIdx.x * TPB + threadIdx.x;
    int v = (g < n) ? cnt[g] : 0;
    s[threadIdx.x] = v;
    __syncthreads();
    for (int off = 1; off < TPB; off <<= 1) {
        int t = (threadIdx.x >= off) ? s[threadIdx.x - off] : 0;
        __syncthreads();
        s[threadIdx.x] += t;
        __syncthreads();
    }
    if (g < n) base[g] = s[threadIdx.x] - v;
    if (threadIdx.x == TPB - 1) bsum[blockIdx.x] = s[threadIdx.x];
}

__global__ void scan2_kernel(int* __restrict__ bsum, int nb) {
    __shared__ int s[TPB];
    int v = (threadIdx.x < nb) ? bsum[threadIdx.x] : 0;
    s[threadIdx.x] = v;
    __syncthreads();
    for (int off = 1; off < TPB; off <<= 1) {
        int t = (threadIdx.x >= off) ? s[threadIdx.x - off] : 0;
        __syncthreads();
        s[threadIdx.x] += t;
        __syncthreads();
    }
    if (threadIdx.x < nb) bsum[threadIdx.x] = s[threadIdx.x] - v;
}

// base[g] -> global start; ptr[g] -> global END (= start + cnt)
__global__ void scan3_kernel(int* __restrict__ base, int* __restrict__ ptr,
                             const int* __restrict__ bsum, const int* __restrict__ cnt, int n) {
    int g = blockIdx.x * TPB + threadIdx.x;
    if (g >= n) return;
    int b = base[g] + bsum[g >> 8];
    base[g] = b;
    ptr[g] = b + cnt[g];
}

// atomic-free scatter: one 4B scattered store per edge
__global__ void scatter_kernel(const int* __restrict__ row, const int* __restrict__ col,
                               const int* __restrict__ base, const int* __restrict__ rank,
                               int* __restrict__ rowp, int er) {
    int e = blockIdx.x * TPB + threadIdx.x;
    if (e >= er) return;
    rowp[base[col[e]] + rank[e]] = row[e];
}

// coalesced segmented fill of colp from the CSR
__global__ void colfill_kernel(const int* __restrict__ base, const int* __restrict__ endp,
                               int* __restrict__ colp, int n) {
    int gid = blockIdx.x * TPB + threadIdx.x;
    int c = gid >> 2;
    int l = gid & 3;
    if (c >= n) return;
    int e_end = endp[c];
    for (int i = base[c] + l; i < e_end; i += 4) colp[i] = c;
}

// ==================== layer-0: inv norm + normalized bf16 copy (16 lanes/node) ====================
__global__ void norm_kernel(const float* __restrict__ feat, float* __restrict__ inv,
                            unsigned* __restrict__ xb, int n) {
    int gid = blockIdx.x * TPB + threadIdx.x;
    int node = gid >> 4;
    int lane = gid & 15;
    if (node >= n) return;
    const float4* fr = (const float4*)(feat + (size_t)node * 128);
    float4 v0 = fr[lane * 2], v1 = fr[lane * 2 + 1];
    float ss = dot4(v0, v0) + dot4(v1, v1);
#pragma unroll
    for (int off = 8; off > 0; off >>= 1) ss += __shfl_xor(ss, off);
    float iv = (ss > 0.f) ? rsqrtf(ss) : 1.0f;
    if (lane == 0) inv[node] = iv;
    uint4 q;
    q.x = pack2(v0.x * iv, v0.y * iv);
    q.y = pack2(v0.z * iv, v0.w * iv);
    q.z = pack2(v1.x * iv, v1.y * iv);
    q.w = pack2(v1.z * iv, v1.w * iv);
    ((uint4*)xb)[(size_t)node * 16 + lane] = q;
}

// ==================== bf16-screened cosine sim, F=128 (16 lanes/edge, 2 edges/thread) ====================
__global__ void simbf_kernel(const unsigned* __restrict__ xb, const float* __restrict__ feat,
                             const float* __restrict__ inv,
                             const int* __restrict__ rowp, const int* __restrict__ colp,
                             float* __restrict__ sim, unsigned long long* __restrict__ rsd,
                             long long ne) {
    constexpr float MARGIN = 0.02f;
    long long half = (ne + 1) >> 1;
    long long gid = (long long)blockIdx.x * TPB + threadIdx.x;
    long long slot = gid >> 4;
    int lane = (int)(gid & 15);
    if (slot >= half) return;
    long long e0 = slot;
    long long e1 = slot + half;
    bool has1 = (e1 < ne);
    if (!has1) e1 = e0;
    int r0 = rowp[e0], c0 = colp[e0];
    int r1 = rowp[e1], c1 = colp[e1];
    const uint4* X = (const uint4*)xb;
    uint4 a0 = X[(size_t)r0 * 16 + lane];
    uint4 b0 = X[(size_t)c0 * 16 + lane];
    uint4 a1 = X[(size_t)r1 * 16 + lane];
    uint4 b1 = X[(size_t)c1 * 16 + lane];
    float s0 = dotu(a0.x, b0.x) + dotu(a0.y, b0.y) + dotu(a0.z, b0.z) + dotu(a0.w, b0.w);
    float s1 = dotu(a1.x, b1.x) + dotu(a1.y, b1.y) + dotu(a1.z, b1.z) + dotu(a1.w, b1.w);
#pragma unroll
    for (int off = 8; off > 0; off >>= 1) {
        s0 += __shfl_xor(s0, off);
        s1 += __shfl_xor(s1, off);
    }
    if (fabsf(s0 - 0.5f) < MARGIN && r0 != c0) {
        const float4* fa = (const float4*)(feat + (size_t)r0 * 128);
        const float4* fb = (const float4*)(feat + (size_t)c0 * 128);
        float d = dot4(fa[lane * 2], fb[lane * 2]) + dot4(fa[lane * 2 + 1], fb[lane * 2 + 1]);
#pragma unroll
        for (int off = 8; off > 0; off >>= 1) d += __shfl_xor(d, off);
        s0 = d * inv[r0] * inv[c0];
    }
    if (has1 && fabsf(s1 - 0.5f) < MARGIN && r1 != c1) {
        const float4* fa = (const float4*)(feat + (size_t)r1 * 128);
        const float4* fb = (const float4*)(feat + (size_t)c1 * 128);
        float d = dot4(fa[lane * 2], fb[lane * 2]) + dot4(fa[lane * 2 + 1], fb[lane * 2 + 1]);
#pragma unroll
        for (int off = 8; off > 0; off >>= 1) d += __shfl_xor(d, off);
        s1 = d * inv[r1] * inv[c1];
    }
    if (lane == 0) {
        if (s0 < 0.5f || r0 == c0) s0 = 0.f;
        sim[e0] = s0;
        if (s0 > 0.f) atomicAdd(&rsd[r0], rsd_pack(s0));
        if (has1) {
            if (s1 < 0.5f || r1 == c1) s1 = 0.f;
            sim[e1] = s1;
            if (s1 > 0.f) atomicAdd(&rsd[r1], rsd_pack(s1));
        }
    }
}

// ==================== fp32 cosine sim for F=16: one edge/thread, one packed atomic ====================
__global__ void sim16_kernel(const float* __restrict__ feat, const float* __restrict__ inv,
                             const int* __restrict__ rowp, const int* __restrict__ colp,
                             float* __restrict__ sim, unsigned long long* __restrict__ rsd,
                             long long ne) {
    long long e = (long long)blockIdx.x * TPB + threadIdx.x;
    if (e >= ne) return;
    int r = rowp[e], c = colp[e];
    const float4* fa = (const float4*)(feat + (size_t)r * 16);
    const float4* fb = (const float4*)(feat + (size_t)c * 16);
    float4 a0 = fa[0], a1 = fa[1], a2 = fa[2], a3 = fa[3];
    float4 b0 = fb[0], b1 = fb[1], b2 = fb[2], b3 = fb[3];
    float s = dot4(a0, b0) + dot4(a1, b1) + dot4(a2, b2) + dot4(a3, b3);
    s *= inv[r] * inv[c];
    if (s < 0.5f || r == c) s = 0.f;
    sim[e] = s;
    if (s > 0.f) atomicAdd(&rsd[r], rsd_pack(s));
}

// ==================== col-segmented: w=exp(sim/rs[row]); deg2[c]=ws_self+Σw ====================
__global__ void wdeg2_kernel(float* __restrict__ ew, const unsigned long long* __restrict__ rsd,
                             const int* __restrict__ rowp,
                             const int* __restrict__ base, const int* __restrict__ endp,
                             float* __restrict__ deg2, float* __restrict__ ws_self, int n) {
    int gid = blockIdx.x * TPB + threadIdx.x;
    int c = gid >> 2;
    int l = gid & 3;
    if (c >= n) return;
    int s = base[c], e_end = endp[c];
    float sum = 0.f;
    for (int e = s + l; e < e_end; e += 4) {
        float sv = ew[e];
        if (sv > 0.f) {
            float w = __expf(sv / rsd_rs(rsd[rowp[e]]));
            ew[e] = w;
            sum += w;
        }
    }
    sum += __shfl_xor(sum, 1, 4);
    sum += __shfl_xor(sum, 2, 4);
    if (l == 0) {
        float wsf = __expf(1.0f / (rsd_deg(rsd[c]) + 1.0f));
        ws_self[c] = wsf;
        deg2[c] = wsf + sum;
    }
}

// ==================== dense h = feat @ W, 128x128: BM=128, 8x8 register tile ====================
// 256 threads: j8 = tid&15 (cols j8*4 and 64+j8*4), sub = tid>>4 (nodes sub + s*16, s=0..7).
// Per 4-k chunk: 16 ds_read_b128 per 256 FMA inst. NO launch_bounds min-waves clause:
// natural VGPR ~130-160 (R14 lesson: capping below the live-set spills to scratch).
__global__ __launch_bounds__(256) void gemm128_kernel(const float* __restrict__ feat,
                                                      const float* __restrict__ W,
                                                      float* __restrict__ out, int n) {
    constexpr int FIN = 128, FOUT = 128, BM = 128, BK = 32, FPAD = 36;
    __shared__ float Wl[BK * FOUT];        // 16 KB
    __shared__ float Fl[BM * FPAD];        // 18 KB
    int tid = threadIdx.x;
    int base = blockIdx.x * BM;
    int j8 = tid & 15;
    int sub = tid >> 4;
    float4 accL[8], accH[8];
#pragma unroll
    for (int s = 0; s < 8; ++s) {
        accL[s] = make_float4(0.f, 0.f, 0.f, 0.f);
        accH[s] = make_float4(0.f, 0.f, 0.f, 0.f);
    }

    for (int t = 0; t < FIN / BK; ++t) {
        int k0 = t * BK;
        if (t > 0) __syncthreads();
#pragma unroll
        for (int i = 0; i < 4; ++i) {   // stage W tile: 1024 float4
            int idx = tid + 256 * i;
            int r = idx >> 5, c4 = idx & 31;
            *(float4*)&Wl[r * FOUT + c4 * 4] =
                *(const float4*)(W + (size_t)(k0 + r) * FOUT + c4 * 4);
        }
#pragma unroll
        for (int i = 0; i < 4; ++i) {   // stage F tile: 1024 float4
            int idx = tid + 256 * i;
            int r = idx >> 3, c4 = idx & 7;
            int node = base + r;
            float4 v = make_float4(0.f, 0.f, 0.f, 0.f);
            if (node < n) v = *(const float4*)(feat + (size_t)node * FIN + k0 + c4 * 4);
            *(float4*)&Fl[r * FPAD + c4 * 4] = v;
        }
        __syncthreads();
#pragma unroll
        for (int k = 0; k < BK; k += 4) {
            float4 wl[4], wh[4];
#pragma unroll
            for (int kk = 0; kk < 4; ++kk) {
                wl[kk] = *(const float4*)&Wl[(k + kk) * FOUT + j8 * 4];
                wh[kk] = *(const float4*)&Wl[(k + kk) * FOUT + 64 + j8 * 4];
            }
#pragma unroll
            for (int s = 0; s < 8; ++s) {
                float4 f = *(const float4*)&Fl[(sub + s * 16) * FPAD + k];
                accL[s].x += f.x * wl[0].x + f.y * wl[1].x + f.z * wl[2].x + f.w * wl[3].x;
                accL[s].y += f.x * wl[0].y + f.y * wl[1].y + f.z * wl[2].y + f.w * wl[3].y;
                accL[s].z += f.x * wl[0].z + f.y * wl[1].z + f.z * wl[2].z + f.w * wl[3].z;
                accL[s].w += f.x * wl[0].w + f.y * wl[1].w + f.z * wl[2].w + f.w * wl[3].w;
                accH[s].x += f.x * wh[0].x + f.y * wh[1].x + f.z * wh[2].x + f.w * wh[3].x;
                accH[s].y += f.x * wh[0].y + f.y * wh[1].y + f.z * wh[2].y + f.w * wh[3].y;
                accH[s].z += f.x * wh[0].z + f.y * wh[1].z + f.z * wh[2].z + f.w * wh[3].z;
                accH[s].w += f.x * wh[0].w + f.y * wh[1].w + f.z * wh[2].w + f.w * wh[3].w;
            }
        }
    }
#pragma unroll
    for (int s = 0; s < 8; ++s) {
        int node = base + sub + s * 16;
        if (node < n) {
            *(float4*)(out + (size_t)node * FOUT + j8 * 4) = accL[s];
            *(float4*)(out + (size_t)node * FOUT + 64 + j8 * 4) = accH[s];
        }
    }
}

// ==================== h = feat @ W for FOUT=16 (4 lanes per node, float4) ====================
template<int FIN>
__global__ void matmulS_kernel(const float* __restrict__ feat, const float* __restrict__ W,
                               float* __restrict__ out, int n) {
    __shared__ float4 Wl[FIN * 4];
    for (int i = threadIdx.x; i < FIN * 4; i += TPB) Wl[i] = ((const float4*)W)[i];
    __syncthreads();
    int gid = blockIdx.x * TPB + threadIdx.x;
    int node = gid >> 2;
    int j4 = gid & 3;
    if (node >= n) return;
    const float4* fr = (const float4*)(feat + (size_t)node * FIN);
    float4 acc = make_float4(0.f, 0.f, 0.f, 0.f);
#pragma unroll
    for (int k4 = 0; k4 < FIN / 4; ++k4) {
        float4 f = fr[k4];
        float4 w0 = Wl[(4 * k4 + 0) * 4 + j4];
        float4 w1 = Wl[(4 * k4 + 1) * 4 + j4];
        float4 w2 = Wl[(4 * k4 + 2) * 4 + j4];
        float4 w3 = Wl[(4 * k4 + 3) * 4 + j4];
        acc.x += f.x * w0.x + f.y * w1.x + f.z * w2.x + f.w * w3.x;
        acc.y += f.x * w0.y + f.y * w1.y + f.z * w2.y + f.w * w3.y;
        acc.z += f.x * w0.z + f.y * w1.z + f.z * w2.z + f.w * w3.z;
        acc.w += f.x * w0.w + f.y * w1.w + f.z * w2.w + f.w * w3.w;
    }
    *((float4*)(out + (size_t)node * 16) + j4) = acc;
}

// ==================== fused segmented aggregate + finalize, F=128 (32 lanes/col) ====================
template<bool RELU>
__global__ void aggfin128_kernel(const float* __restrict__ h, const float* __restrict__ ew,
                                 const float* __restrict__ deg2, const int* __restrict__ rowp,
                                 const int* __restrict__ base, const int* __restrict__ endp,
                                 const float* __restrict__ ws_self, const float* __restrict__ b,
                                 float* __restrict__ outb, float* __restrict__ inv,
                                 unsigned* __restrict__ xb, int n) {
    int gid = blockIdx.x * TPB + threadIdx.x;
    int c = gid >> 5;
    int j4 = gid & 31;
    if (c >= n) return;
    int s = base[c], e_end = endp[c];
    float d2c = deg2[c];
    float dc = rsqrtf(d2c);
    float4 acc = make_float4(0.f, 0.f, 0.f, 0.f);
    for (int e = s; e < e_end; ++e) {
        float we = ew[e];
        if (we == 0.f) continue;
        int r = rowp[e];
        float nw = rsqrtf(deg2[r]) * we * dc;
        float4 hv = *((const float4*)(h + (size_t)r * 128) + j4);
        acc.x += nw * hv.x; acc.y += nw * hv.y; acc.z += nw * hv.z; acc.w += nw * hv.w;
    }
    float nws = ws_self[c] / d2c;
    float4 hv = *((const float4*)(h + (size_t)c * 128) + j4);
    float4 bv = ((const float4*)b)[j4];
    float4 o;
    o.x = acc.x + nws * hv.x + bv.x;
    o.y = acc.y + nws * hv.y + bv.y;
    o.z = acc.z + nws * hv.z + bv.z;
    o.w = acc.w + nws * hv.w + bv.w;
    if (RELU) {
        o.x = fmaxf(o.x, 0.f); o.y = fmaxf(o.y, 0.f);
        o.z = fmaxf(o.z, 0.f); o.w = fmaxf(o.w, 0.f);
    }
    *((float4*)(outb + (size_t)c * 128) + j4) = o;
    float ss = o.x * o.x + o.y * o.y + o.z * o.z + o.w * o.w;
#pragma unroll
    for (int off = 16; off > 0; off >>= 1)
        ss += __shfl_xor(ss, off, 32);
    float iv = (ss > 0.f) ? rsqrtf(ss) : 1.0f;
    if (j4 == 0) inv[c] = iv;
    uint2 p;
    p.x = pack2(o.x * iv, o.y * iv);
    p.y = pack2(o.z * iv, o.w * iv);
    ((uint2*)xb)[(size_t)c * 32 + j4] = p;
}

// ==================== fused segmented aggregate + finalize, F=16 (4 lanes/col) ====================
template<bool RELU, bool LOGSM, bool WINV>
__global__ void aggfin16_kernel(const float* __restrict__ h, const float* __restrict__ ew,
                                const float* __restrict__ deg2, const int* __restrict__ rowp,
                                const int* __restrict__ base, const int* __restrict__ endp,
                                const float* __restrict__ ws_self, const float* __restrict__ b,
                                float* __restrict__ out, float* __restrict__ inv, int n) {
    int gid = blockIdx.x * TPB + threadIdx.x;
    int c = gid >> 2;
    int l = gid & 3;
    if (c >= n) return;
    int s = base[c], e_end = endp[c];
    float d2c = deg2[c];
    float dc = rsqrtf(d2c);
    float4 acc = make_float4(0.f, 0.f, 0.f, 0.f);
    for (int e = s; e < e_end; ++e) {
        float we = ew[e];
        if (we == 0.f) continue;
        int r = rowp[e];
        float nw = rsqrtf(deg2[r]) * we * dc;
        float4 hv = *((const float4*)(h + (size_t)r * 16) + l);
        acc.x += nw * hv.x; acc.y += nw * hv.y; acc.z += nw * hv.z; acc.w += nw * hv.w;
    }
    float nws = ws_self[c] / d2c;
    float4 hv = *((const float4*)(h + (size_t)c * 16) + l);
    float4 bv = ((const float4*)b)[l];
    float4 v;
    v.x = acc.x + nws * hv.x + bv.x;
    v.y = acc.y + nws * hv.y + bv.y;
    v.z = acc.z + nws * hv.z + bv.z;
    v.w = acc.w + nws * hv.w + bv.w;
    if (RELU) {
        v.x = fmaxf(v.x, 0.f); v.y = fmaxf(v.y, 0.f);
        v.z = fmaxf(v.z, 0.f); v.w = fmaxf(v.w, 0.f);
    }
    if (WINV) {
        float ss = v.x * v.x + v.y * v.y + v.z * v.z + v.w * v.w;
        ss += __shfl_xor(ss, 1, 4);
        ss += __shfl_xor(ss, 2, 4);
        if (l == 0) inv[c] = (ss > 0.f) ? rsqrtf(ss) : 1.0f;
    }
    if (LOGSM) {
        float m = fmaxf(fmaxf(v.x, v.y), fmaxf(v.z, v.w));
        m = fmaxf(m, __shfl_xor(m, 1, 4));
        m = fmaxf(m, __shfl_xor(m, 2, 4));
        float sm = expf(v.x - m) + expf(v.y - m) + expf(v.z - m) + expf(v.w - m);
        sm += __shfl_xor(sm, 1, 4);
        sm += __shfl_xor(sm, 2, 4);
        float ls = m + logf(sm);
        v.x -= ls; v.y -= ls; v.z -= ls; v.w -= ls;
    }
    *((float4*)(out + (size_t)c * 16) + l) = v;
}

extern "C" void kernel_launch(void* const* d_in, const int* in_sizes, int n_in,
                              void* d_out, int out_size, void* d_ws, size_t ws_size,
                              hipStream_t stream) {
    const float* x  = (const float*)d_in[0];
    const int*   row = (const int*)d_in[1];
    const int*   col = (const int*)d_in[2];
    const float* W0 = (const float*)d_in[3];
    const float* b0 = (const float*)d_in[4];
    const float* W1 = (const float*)d_in[5];
    const float* b1 = (const float*)d_in[6];
    const float* W2 = (const float*)d_in[7];
    const float* b2 = (const float*)d_in[8];

    const int NFEAT = 128, NHID = 128;
    int N = in_sizes[0] / NFEAT;            // 50000
    long long E = in_sizes[1];              // 850000 (tail N are self-loops)
    long long Er = E - N;                   // 800000 random edges
    int er = (int)Er;

    float* ws = (float*)d_ws;
    float* A       = ws;                          // [N,128] h
    float* B       = A + (size_t)N * NHID;        // [N,128] feat buffer
    float* ew      = B + (size_t)N * NHID;        // [Er] sim -> w (col-sorted order)
    unsigned long long* rsd = (unsigned long long*)(ew + Er);   // [N] packed rs|deg
    float* inv     = (float*)(rsd + N);           // [N]
    float* deg2    = inv + N;                     // [N]
    float* ws_self = deg2 + N;                    // [N]
    int* cnt    = (int*)(ws_self + N);            // [N]
    int* base   = cnt + N;                        // [N] col-CSR starts
    int* ptr    = base + N;                       // [N] col-CSR ends
    int* bsum   = ptr + N;                        // [256]
    int* rank   = bsum + 256;                     // [Er] within-col rank
    int* rowp   = rank + Er;                      // [Er]
    int* colp   = rowp + Er;                      // [Er]
    unsigned* xb = (unsigned*)(colp + Er);        // [N*64] bf16x2 packed
    float* out  = (float*)d_out;                  // [N,16]

    int nb = (N + TPB - 1) / TPB;
    unsigned egrid = (unsigned)((er + TPB - 1) / TPB);
    unsigned n4grid = (unsigned)(((long long)N * 4 + TPB - 1) / TPB);

    // ---- col sort -> col-CSR; scatter has NO atomics (rank precomputed in hist) ----
    hipMemsetAsync(cnt, 0, sizeof(int) * (size_t)N, stream);
    hist_kernel<<<egrid, TPB, 0, stream>>>(col, cnt, rank, er);
    scan1_kernel<<<nb, TPB, 0, stream>>>(cnt, base, bsum, N);
    scan2_kernel<<<1, TPB, 0, stream>>>(bsum, nb);
    scan3_kernel<<<nb, TPB, 0, stream>>>(base, ptr, bsum, cnt, N);
    scatter_kernel<<<egrid, TPB, 0, stream>>>(row, col, base, rank, rowp, er);
    colfill_kernel<<<n4grid, TPB, 0, stream>>>(base, ptr, colp, N);

    // layer-0 norms + bf16 copy
    norm_kernel<<<(unsigned)(((long long)N * 16 + TPB - 1) / TPB), TPB, 0, stream>>>(x, inv, xb, N);

    long long half = (Er + 1) >> 1;
    unsigned simgrid = (unsigned)((half * 16 + TPB - 1) / TPB);

    // ---------------- layer 0: x[N,128] -> B[N,128], relu ----------------
    hipMemsetAsync(rsd, 0, sizeof(unsigned long long) * (size_t)N, stream);
    simbf_kernel<<<simgrid, TPB, 0, stream>>>(xb, x, inv, rowp, colp, ew, rsd, Er);
    wdeg2_kernel<<<n4grid, TPB, 0, stream>>>(ew, rsd, rowp, base, ptr, deg2, ws_self, N);
    gemm128_kernel<<<(unsigned)((N + 127) / 128), 256, 0, stream>>>(x, W0, A, N);
    aggfin128_kernel<true><<<(unsigned)(((long long)N * 32 + TPB - 1) / TPB), TPB, 0, stream>>>(
        A, ew, deg2, rowp, base, ptr, ws_self, b0, B, inv, xb, N);

    // ---------------- layer 1: B[N,128] -> B[N,16], relu ----------------
    hipMemsetAsync(rsd, 0, sizeof(unsigned long long) * (size_t)N, stream);
    simbf_kernel<<<simgrid, TPB, 0, stream>>>(xb, B, inv, rowp, colp, ew, rsd, Er);
    wdeg2_kernel<<<n4grid, TPB, 0, stream>>>(ew, rsd, rowp, base, ptr, deg2, ws_self, N);
    matmulS_kernel<128><<<n4grid, TPB, 0, stream>>>(B, W1, A, N);
    aggfin16_kernel<true, false, true><<<n4grid, TPB, 0, stream>>>(
        A, ew, deg2, rowp, base, ptr, ws_self, b1, B, inv, N);

    // ---------------- layer 2: B[N,16] -> out[N,16], log_softmax ----------------
    hipMemsetAsync(rsd, 0, sizeof(unsigned long long) * (size_t)N, stream);
    sim16_kernel<<<egrid, TPB, 0, stream>>>(B, inv, rowp, colp, ew, rsd, Er);
    wdeg2_kernel<<<n4grid, TPB, 0, stream>>>(ew, rsd, rowp, base, ptr, deg2, ws_self, N);
    matmulS_kernel<16><<<n4grid, TPB, 0, stream>>>(B, W2, A, N);
    aggfin16_kernel<false, true, false><<<n4grid, TPB, 0, stream>>>(
        A, ew, deg2, rowp, base, ptr, ws_self, b2, out, inv, N);
}

// Round 16
// 317.371 us; speedup vs baseline: 1.6352x; 1.0381x over previous
//
#include <hip/hip_runtime.h>

static constexpr int TPB = 256;

// ---- bf16 helpers ----
__device__ __forceinline__ unsigned bf16rne(float x) {
    unsigned u = __float_as_uint(x);
    return (u + 0x7fffu + ((u >> 16) & 1u)) >> 16;
}
__device__ __forceinline__ unsigned pack2(float a, float b) {
    return bf16rne(a) | (bf16rne(b) << 16);
}
__device__ __forceinline__ float dotu(unsigned a, unsigned b) {
    float alo = __uint_as_float(a << 16), ahi = __uint_as_float(a & 0xffff0000u);
    float blo = __uint_as_float(b << 16), bhi = __uint_as_float(b & 0xffff0000u);
    return alo * blo + ahi * bhi;
}
__device__ __forceinline__ float dot4(float4 a, float4 b) {
    return a.x * b.x + a.y * b.y + a.z * b.z + a.w * b.w;
}

// ---- fixed-point packed rs/deg: deg in bits [44..63], rs*2^20 in bits [0..43] ----
__device__ __forceinline__ unsigned long long rsd_pack(float s) {
    return (1ull << 44) | (unsigned long long)__float2uint_rn(s * 1048576.0f);
}
__device__ __forceinline__ float rsd_rs(unsigned long long v) {
    return (float)(v & 0xFFFFFFFFFFFull) * (1.0f / 1048576.0f);
}
__device__ __forceinline__ float rsd_deg(unsigned long long v) {
    return (float)(unsigned)(v >> 44);
}

// ==================== col counting sort -> col-CSR (atomic-free scatter) ====================
__global__ void hist_kernel(const int* __restrict__ col, int* __restrict__ cnt,
                            int* __restrict__ rank, int er) {
    int e = blockIdx.x * TPB + threadIdx.x;
    if (e >= er) return;
    rank[e] = atomicAdd(&cnt[col[e]], 1);
}

__global__ void scan1_kernel(const int* __restrict__ cnt, int* __restrict__ base,
                             int* __restrict__ bsum, int n) {
    __shared__ int s[TPB];
    int g = blockIdx.x * TPB + threadIdx.x;
    int v = (g < n) ? cnt[g] : 0;
    s[threadIdx.x] = v;
    __syncthreads();
    for (int off = 1; off < TPB; off <<= 1) {
        int t = (threadIdx.x >= off) ? s[threadIdx.x - off] : 0;
        __syncthreads();
        s[threadIdx.x] += t;
        __syncthreads();
    }
    if (g < n) base[g] = s[threadIdx.x] - v;
    if (threadIdx.x == TPB - 1) bsum[blockIdx.x] = s[threadIdx.x];
}

__global__ void scan2_kernel(int* __restrict__ bsum, int nb) {
    __shared__ int s[TPB];
    int v = (threadIdx.x < nb) ? bsum[threadIdx.x] : 0;
    s[threadIdx.x] = v;
    __syncthreads();
    for (int off = 1; off < TPB; off <<= 1) {
        int t = (threadIdx.x >= off) ? s[threadIdx.x - off] : 0;
        __syncthreads();
        s[threadIdx.x] += t;
        __syncthreads();
    }
    if (threadIdx.x < nb) bsum[threadIdx.x] = s[threadIdx.x] - v;
}

// base[g] -> global start; ptr[g] -> global END (= start + cnt)
__global__ void scan3_kernel(int* __restrict__ base, int* __restrict__ ptr,
                             const int* __restrict__ bsum, const int* __restrict__ cnt, int n) {
    int g = blockIdx.x * TPB + threadIdx.x;
    if (g >= n) return;
    int b = base[g] + bsum[g >> 8];
    base[g] = b;
    ptr[g] = b + cnt[g];
}

// atomic-free scatter: one 4B scattered store per edge
__global__ void scatter_kernel(const int* __restrict__ row, const int* __restrict__ col,
                               const int* __restrict__ base, const int* __restrict__ rank,
                               int* __restrict__ rowp, int er) {
    int e = blockIdx.x * TPB + threadIdx.x;
    if (e >= er) return;
    rowp[base[col[e]] + rank[e]] = row[e];
}

// coalesced segmented fill of colp from the CSR
__global__ void colfill_kernel(const int* __restrict__ base, const int* __restrict__ endp,
                               int* __restrict__ colp, int n) {
    int gid = blockIdx.x * TPB + threadIdx.x;
    int c = gid >> 2;
    int l = gid & 3;
    if (c >= n) return;
    int e_end = endp[c];
    for (int i = base[c] + l; i < e_end; i += 4) colp[i] = c;
}

// ==================== layer-0: inv norm + normalized bf16 copy (16 lanes/node) ====================
__global__ void norm_kernel(const float* __restrict__ feat, float* __restrict__ inv,
                            unsigned* __restrict__ xb, int n) {
    int gid = blockIdx.x * TPB + threadIdx.x;
    int node = gid >> 4;
    int lane = gid & 15;
    if (node >= n) return;
    const float4* fr = (const float4*)(feat + (size_t)node * 128);
    float4 v0 = fr[lane * 2], v1 = fr[lane * 2 + 1];
    float ss = dot4(v0, v0) + dot4(v1, v1);
#pragma unroll
    for (int off = 8; off > 0; off >>= 1) ss += __shfl_xor(ss, off);
    float iv = (ss > 0.f) ? rsqrtf(ss) : 1.0f;
    if (lane == 0) inv[node] = iv;
    uint4 q;
    q.x = pack2(v0.x * iv, v0.y * iv);
    q.y = pack2(v0.z * iv, v0.w * iv);
    q.z = pack2(v1.x * iv, v1.y * iv);
    q.w = pack2(v1.z * iv, v1.w * iv);
    ((uint4*)xb)[(size_t)node * 16 + lane] = q;
}

// ==================== bf16-screened cosine sim, F=128 (16 lanes/edge, 2 edges/thread) ====================
__global__ void simbf_kernel(const unsigned* __restrict__ xb, const float* __restrict__ feat,
                             const float* __restrict__ inv,
                             const int* __restrict__ rowp, const int* __restrict__ colp,
                             float* __restrict__ sim, unsigned long long* __restrict__ rsd,
                             long long ne) {
    constexpr float MARGIN = 0.02f;
    long long half = (ne + 1) >> 1;
    long long gid = (long long)blockIdx.x * TPB + threadIdx.x;
    long long slot = gid >> 4;
    int lane = (int)(gid & 15);
    if (slot >= half) return;
    long long e0 = slot;
    long long e1 = slot + half;
    bool has1 = (e1 < ne);
    if (!has1) e1 = e0;
    int r0 = rowp[e0], c0 = colp[e0];
    int r1 = rowp[e1], c1 = colp[e1];
    const uint4* X = (const uint4*)xb;
    uint4 a0 = X[(size_t)r0 * 16 + lane];
    uint4 b0 = X[(size_t)c0 * 16 + lane];
    uint4 a1 = X[(size_t)r1 * 16 + lane];
    uint4 b1 = X[(size_t)c1 * 16 + lane];
    float s0 = dotu(a0.x, b0.x) + dotu(a0.y, b0.y) + dotu(a0.z, b0.z) + dotu(a0.w, b0.w);
    float s1 = dotu(a1.x, b1.x) + dotu(a1.y, b1.y) + dotu(a1.z, b1.z) + dotu(a1.w, b1.w);
#pragma unroll
    for (int off = 8; off > 0; off >>= 1) {
        s0 += __shfl_xor(s0, off);
        s1 += __shfl_xor(s1, off);
    }
    if (fabsf(s0 - 0.5f) < MARGIN && r0 != c0) {
        const float4* fa = (const float4*)(feat + (size_t)r0 * 128);
        const float4* fb = (const float4*)(feat + (size_t)c0 * 128);
        float d = dot4(fa[lane * 2], fb[lane * 2]) + dot4(fa[lane * 2 + 1], fb[lane * 2 + 1]);
#pragma unroll
        for (int off = 8; off > 0; off >>= 1) d += __shfl_xor(d, off);
        s0 = d * inv[r0] * inv[c0];
    }
    if (has1 && fabsf(s1 - 0.5f) < MARGIN && r1 != c1) {
        const float4* fa = (const float4*)(feat + (size_t)r1 * 128);
        const float4* fb = (const float4*)(feat + (size_t)c1 * 128);
        float d = dot4(fa[lane * 2], fb[lane * 2]) + dot4(fa[lane * 2 + 1], fb[lane * 2 + 1]);
#pragma unroll
        for (int off = 8; off > 0; off >>= 1) d += __shfl_xor(d, off);
        s1 = d * inv[r1] * inv[c1];
    }
    if (lane == 0) {
        if (s0 < 0.5f || r0 == c0) s0 = 0.f;
        sim[e0] = s0;
        if (s0 > 0.f) atomicAdd(&rsd[r0], rsd_pack(s0));
        if (has1) {
            if (s1 < 0.5f || r1 == c1) s1 = 0.f;
            sim[e1] = s1;
            if (s1 > 0.f) atomicAdd(&rsd[r1], rsd_pack(s1));
        }
    }
}

// ==================== fp32 cosine sim for F=16: one edge/thread, one packed atomic ====================
__global__ void sim16_kernel(const float* __restrict__ feat, const float* __restrict__ inv,
                             const int* __restrict__ rowp, const int* __restrict__ colp,
                             float* __restrict__ sim, unsigned long long* __restrict__ rsd,
                             long long ne) {
    long long e = (long long)blockIdx.x * TPB + threadIdx.x;
    if (e >= ne) return;
    int r = rowp[e], c = colp[e];
    const float4* fa = (const float4*)(feat + (size_t)r * 16);
    const float4* fb = (const float4*)(feat + (size_t)c * 16);
    float4 a0 = fa[0], a1 = fa[1], a2 = fa[2], a3 = fa[3];
    float4 b0 = fb[0], b1 = fb[1], b2 = fb[2], b3 = fb[3];
    float s = dot4(a0, b0) + dot4(a1, b1) + dot4(a2, b2) + dot4(a3, b3);
    s *= inv[r] * inv[c];
    if (s < 0.5f || r == c) s = 0.f;
    sim[e] = s;
    if (s > 0.f) atomicAdd(&rsd[r], rsd_pack(s));
}

// ==================== col-segmented: w=exp(sim/rs[row]); deg2[c]=ws_self+Σw ====================
__global__ void wdeg2_kernel(float* __restrict__ ew, const unsigned long long* __restrict__ rsd,
                             const int* __restrict__ rowp,
                             const int* __restrict__ base, const int* __restrict__ endp,
                             float* __restrict__ deg2, float* __restrict__ ws_self, int n) {
    int gid = blockIdx.x * TPB + threadIdx.x;
    int c = gid >> 2;
    int l = gid & 3;
    if (c >= n) return;
    int s = base[c], e_end = endp[c];
    float sum = 0.f;
    for (int e = s + l; e < e_end; e += 4) {
        float sv = ew[e];
        if (sv > 0.f) {
            float w = __expf(sv / rsd_rs(rsd[rowp[e]]));
            ew[e] = w;
            sum += w;
        }
    }
    sum += __shfl_xor(sum, 1, 4);
    sum += __shfl_xor(sum, 2, 4);
    if (l == 0) {
        float wsf = __expf(1.0f / (rsd_deg(rsd[c]) + 1.0f));
        ws_self[c] = wsf;
        deg2[c] = wsf + sum;
    }
}

// ==================== dense h = feat @ W, 128x128: BM=128 x BN=64, 8x4 register tile ====================
// grid = 2*ceil(N/128); blockIdx.x&1 selects col half. 256 threads: j4 = tid&15 (4 cols),
// sub = tid>>4 (nodes sub + s*16, s=0..7). Per 4-k chunk: 12 ds_read_b128 per 128 FMA inst
// (2.25x LDS oversubscription vs R13's 3x). Live-set ~100 VGPR; cap 128 (2 waves/SIMD) is safe.
__global__ __launch_bounds__(256, 2) void gemm128_kernel(const float* __restrict__ feat,
                                                         const float* __restrict__ W,
                                                         float* __restrict__ out, int n) {
    constexpr int FIN = 128, FOUT = 128, BM = 128, BK = 32, FPAD = 36;
    __shared__ float Wl[BK * 64];          // 8 KB
    __shared__ float Fl[BM * FPAD];        // 18 KB
    int tid = threadIdx.x;
    int bm = blockIdx.x >> 1;
    int half = blockIdx.x & 1;
    int base = bm * BM;
    int j4 = tid & 15;
    int sub = tid >> 4;
    float4 acc[8];
#pragma unroll
    for (int s = 0; s < 8; ++s) acc[s] = make_float4(0.f, 0.f, 0.f, 0.f);

    for (int t = 0; t < FIN / BK; ++t) {
        int k0 = t * BK;
        if (t > 0) __syncthreads();
#pragma unroll
        for (int i = 0; i < 2; ++i) {   // stage W tile 32x64: 512 float4
            int idx = tid + 256 * i;
            int r = idx >> 4, c4 = idx & 15;
            *(float4*)&Wl[r * 64 + c4 * 4] =
                *(const float4*)(W + (size_t)(k0 + r) * FOUT + half * 64 + c4 * 4);
        }
#pragma unroll
        for (int i = 0; i < 4; ++i) {   // stage F tile 128x32: 1024 float4
            int idx = tid + 256 * i;
            int r = idx >> 3, c4 = idx & 7;
            int node = base + r;
            float4 v = make_float4(0.f, 0.f, 0.f, 0.f);
            if (node < n) v = *(const float4*)(feat + (size_t)node * FIN + k0 + c4 * 4);
            *(float4*)&Fl[r * FPAD + c4 * 4] = v;
        }
        __syncthreads();
#pragma unroll
        for (int k = 0; k < BK; k += 4) {
            float4 w0 = *(const float4*)&Wl[(k + 0) * 64 + j4 * 4];
            float4 w1 = *(const float4*)&Wl[(k + 1) * 64 + j4 * 4];
            float4 w2 = *(const float4*)&Wl[(k + 2) * 64 + j4 * 4];
            float4 w3 = *(const float4*)&Wl[(k + 3) * 64 + j4 * 4];
#pragma unroll
            for (int s = 0; s < 8; ++s) {
                float4 f = *(const float4*)&Fl[(sub + s * 16) * FPAD + k];
                acc[s].x += f.x * w0.x + f.y * w1.x + f.z * w2.x + f.w * w3.x;
                acc[s].y += f.x * w0.y + f.y * w1.y + f.z * w2.y + f.w * w3.y;
                acc[s].z += f.x * w0.z + f.y * w1.z + f.z * w2.z + f.w * w3.z;
                acc[s].w += f.x * w0.w + f.y * w1.w + f.z * w2.w + f.w * w3.w;
            }
        }
    }
#pragma unroll
    for (int s = 0; s < 8; ++s) {
        int node = base + sub + s * 16;
        if (node < n)
            *(float4*)(out + (size_t)node * FOUT + half * 64 + j4 * 4) = acc[s];
    }
}

// ==================== h = feat @ W for FOUT=16 (4 lanes per node, float4) ====================
template<int FIN>
__global__ void matmulS_kernel(const float* __restrict__ feat, const float* __restrict__ W,
                               float* __restrict__ out, int n) {
    __shared__ float4 Wl[FIN * 4];
    for (int i = threadIdx.x; i < FIN * 4; i += TPB) Wl[i] = ((const float4*)W)[i];
    __syncthreads();
    int gid = blockIdx.x * TPB + threadIdx.x;
    int node = gid >> 2;
    int j4 = gid & 3;
    if (node >= n) return;
    const float4* fr = (const float4*)(feat + (size_t)node * FIN);
    float4 acc = make_float4(0.f, 0.f, 0.f, 0.f);
#pragma unroll
    for (int k4 = 0; k4 < FIN / 4; ++k4) {
        float4 f = fr[k4];
        float4 w0 = Wl[(4 * k4 + 0) * 4 + j4];
        float4 w1 = Wl[(4 * k4 + 1) * 4 + j4];
        float4 w2 = Wl[(4 * k4 + 2) * 4 + j4];
        float4 w3 = Wl[(4 * k4 + 3) * 4 + j4];
        acc.x += f.x * w0.x + f.y * w1.x + f.z * w2.x + f.w * w3.x;
        acc.y += f.x * w0.y + f.y * w1.y + f.z * w2.y + f.w * w3.y;
        acc.z += f.x * w0.z + f.y * w1.z + f.z * w2.z + f.w * w3.z;
        acc.w += f.x * w0.w + f.y * w1.w + f.z * w2.w + f.w * w3.w;
    }
    *((float4*)(out + (size_t)node * 16) + j4) = acc;
}

// ==================== fused segmented aggregate + finalize, F=128 (32 lanes/col) ====================
template<bool RELU>
__global__ void aggfin128_kernel(const float* __restrict__ h, const float* __restrict__ ew,
                                 const float* __restrict__ deg2, const int* __restrict__ rowp,
                                 const int* __restrict__ base, const int* __restrict__ endp,
                                 const float* __restrict__ ws_self, const float* __restrict__ b,
                                 float* __restrict__ outb, float* __restrict__ inv,
                                 unsigned* __restrict__ xb, int n) {
    int gid = blockIdx.x * TPB + threadIdx.x;
    int c = gid >> 5;
    int j4 = gid & 31;
    if (c >= n) return;
    int s = base[c], e_end = endp[c];
    float d2c = deg2[c];
    float dc = rsqrtf(d2c);
    float4 acc = make_float4(0.f, 0.f, 0.f, 0.f);
    for (int e = s; e < e_end; ++e) {
        float we = ew[e];
        if (we == 0.f) continue;
        int r = rowp[e];
        float nw = rsqrtf(deg2[r]) * we * dc;
        float4 hv = *((const float4*)(h + (size_t)r * 128) + j4);
        acc.x += nw * hv.x; acc.y += nw * hv.y; acc.z += nw * hv.z; acc.w += nw * hv.w;
    }
    float nws = ws_self[c] / d2c;
    float4 hv = *((const float4*)(h + (size_t)c * 128) + j4);
    float4 bv = ((const float4*)b)[j4];
    float4 o;
    o.x = acc.x + nws * hv.x + bv.x;
    o.y = acc.y + nws * hv.y + bv.y;
    o.z = acc.z + nws * hv.z + bv.z;
    o.w = acc.w + nws * hv.w + bv.w;
    if (RELU) {
        o.x = fmaxf(o.x, 0.f); o.y = fmaxf(o.y, 0.f);
        o.z = fmaxf(o.z, 0.f); o.w = fmaxf(o.w, 0.f);
    }
    *((float4*)(outb + (size_t)c * 128) + j4) = o;
    float ss = o.x * o.x + o.y * o.y + o.z * o.z + o.w * o.w;
#pragma unroll
    for (int off = 16; off > 0; off >>= 1)
        ss += __shfl_xor(ss, off, 32);
    float iv = (ss > 0.f) ? rsqrtf(ss) : 1.0f;
    if (j4 == 0) inv[c] = iv;
    uint2 p;
    p.x = pack2(o.x * iv, o.y * iv);
    p.y = pack2(o.z * iv, o.w * iv);
    ((uint2*)xb)[(size_t)c * 32 + j4] = p;
}

// ==================== fused segmented aggregate + finalize, F=16 (4 lanes/col) ====================
template<bool RELU, bool LOGSM, bool WINV>
__global__ void aggfin16_kernel(const float* __restrict__ h, const float* __restrict__ ew,
                                const float* __restrict__ deg2, const int* __restrict__ rowp,
                                const int* __restrict__ base, const int* __restrict__ endp,
                                const float* __restrict__ ws_self, const float* __restrict__ b,
                                float* __restrict__ out, float* __restrict__ inv, int n) {
    int gid = blockIdx.x * TPB + threadIdx.x;
    int c = gid >> 2;
    int l = gid & 3;
    if (c >= n) return;
    int s = base[c], e_end = endp[c];
    float d2c = deg2[c];
    float dc = rsqrtf(d2c);
    float4 acc = make_float4(0.f, 0.f, 0.f, 0.f);
    for (int e = s; e < e_end; ++e) {
        float we = ew[e];
        if (we == 0.f) continue;
        int r = rowp[e];
        float nw = rsqrtf(deg2[r]) * we * dc;
        float4 hv = *((const float4*)(h + (size_t)r * 16) + l);
        acc.x += nw * hv.x; acc.y += nw * hv.y; acc.z += nw * hv.z; acc.w += nw * hv.w;
    }
    float nws = ws_self[c] / d2c;
    float4 hv = *((const float4*)(h + (size_t)c * 16) + l);
    float4 bv = ((const float4*)b)[l];
    float4 v;
    v.x = acc.x + nws * hv.x + bv.x;
    v.y = acc.y + nws * hv.y + bv.y;
    v.z = acc.z + nws * hv.z + bv.z;
    v.w = acc.w + nws * hv.w + bv.w;
    if (RELU) {
        v.x = fmaxf(v.x, 0.f); v.y = fmaxf(v.y, 0.f);
        v.z = fmaxf(v.z, 0.f); v.w = fmaxf(v.w, 0.f);
    }
    if (WINV) {
        float ss = v.x * v.x + v.y * v.y + v.z * v.z + v.w * v.w;
        ss += __shfl_xor(ss, 1, 4);
        ss += __shfl_xor(ss, 2, 4);
        if (l == 0) inv[c] = (ss > 0.f) ? rsqrtf(ss) : 1.0f;
    }
    if (LOGSM) {
        float m = fmaxf(fmaxf(v.x, v.y), fmaxf(v.z, v.w));
        m = fmaxf(m, __shfl_xor(m, 1, 4));
        m = fmaxf(m, __shfl_xor(m, 2, 4));
        float sm = expf(v.x - m) + expf(v.y - m) + expf(v.z - m) + expf(v.w - m);
        sm += __shfl_xor(sm, 1, 4);
        sm += __shfl_xor(sm, 2, 4);
        float ls = m + logf(sm);
        v.x -= ls; v.y -= ls; v.z -= ls; v.w -= ls;
    }
    *((float4*)(out + (size_t)c * 16) + l) = v;
}

extern "C" void kernel_launch(void* const* d_in, const int* in_sizes, int n_in,
                              void* d_out, int out_size, void* d_ws, size_t ws_size,
                              hipStream_t stream) {
    const float* x  = (const float*)d_in[0];
    const int*   row = (const int*)d_in[1];
    const int*   col = (const int*)d_in[2];
    const float* W0 = (const float*)d_in[3];
    const float* b0 = (const float*)d_in[4];
    const float* W1 = (const float*)d_in[5];
    const float* b1 = (const float*)d_in[6];
    const float* W2 = (const float*)d_in[7];
    const float* b2 = (const float*)d_in[8];

    const int NFEAT = 128, NHID = 128;
    int N = in_sizes[0] / NFEAT;            // 50000
    long long E = in_sizes[1];              // 850000 (tail N are self-loops)
    long long Er = E - N;                   // 800000 random edges
    int er = (int)Er;

    float* ws = (float*)d_ws;
    float* A       = ws;                          // [N,128] h
    float* B       = A + (size_t)N * NHID;        // [N,128] feat buffer
    float* ew      = B + (size_t)N * NHID;        // [Er] sim -> w (col-sorted order)
    unsigned long long* rsd = (unsigned long long*)(ew + Er);   // [N] packed rs|deg
    float* inv     = (float*)(rsd + N);           // [N]
    float* deg2    = inv + N;                     // [N]
    float* ws_self = deg2 + N;                    // [N]
    int* cnt    = (int*)(ws_self + N);            // [N]
    int* base   = cnt + N;                        // [N] col-CSR starts
    int* ptr    = base + N;                       // [N] col-CSR ends
    int* bsum   = ptr + N;                        // [256]
    int* rank   = bsum + 256;                     // [Er] within-col rank
    int* rowp   = rank + Er;                      // [Er]
    int* colp   = rowp + Er;                      // [Er]
    unsigned* xb = (unsigned*)(colp + Er);        // [N*64] bf16x2 packed
    float* out  = (float*)d_out;                  // [N,16]

    int nb = (N + TPB - 1) / TPB;
    unsigned egrid = (unsigned)((er + TPB - 1) / TPB);
    unsigned n4grid = (unsigned)(((long long)N * 4 + TPB - 1) / TPB);

    // ---- col sort -> col-CSR; scatter has NO atomics (rank precomputed in hist) ----
    hipMemsetAsync(cnt, 0, sizeof(int) * (size_t)N, stream);
    hist_kernel<<<egrid, TPB, 0, stream>>>(col, cnt, rank, er);
    scan1_kernel<<<nb, TPB, 0, stream>>>(cnt, base, bsum, N);
    scan2_kernel<<<1, TPB, 0, stream>>>(bsum, nb);
    scan3_kernel<<<nb, TPB, 0, stream>>>(base, ptr, bsum, cnt, N);
    scatter_kernel<<<egrid, TPB, 0, stream>>>(row, col, base, rank, rowp, er);
    colfill_kernel<<<n4grid, TPB, 0, stream>>>(base, ptr, colp, N);

    // layer-0 norms + bf16 copy
    norm_kernel<<<(unsigned)(((long long)N * 16 + TPB - 1) / TPB), TPB, 0, stream>>>(x, inv, xb, N);

    long long half = (Er + 1) >> 1;
    unsigned simgrid = (unsigned)((half * 16 + TPB - 1) / TPB);

    // ---------------- layer 0: x[N,128] -> B[N,128], relu ----------------
    hipMemsetAsync(rsd, 0, sizeof(unsigned long long) * (size_t)N, stream);
    simbf_kernel<<<simgrid, TPB, 0, stream>>>(xb, x, inv, rowp, colp, ew, rsd, Er);
    wdeg2_kernel<<<n4grid, TPB, 0, stream>>>(ew, rsd, rowp, base, ptr, deg2, ws_self, N);
    gemm128_kernel<<<(unsigned)(2 * ((N + 127) / 128)), 256, 0, stream>>>(x, W0, A, N);
    aggfin128_kernel<true><<<(unsigned)(((long long)N * 32 + TPB - 1) / TPB), TPB, 0, stream>>>(
        A, ew, deg2, rowp, base, ptr, ws_self, b0, B, inv, xb, N);

    // ---------------- layer 1: B[N,128] -> B[N,16], relu ----------------
    hipMemsetAsync(rsd, 0, sizeof(unsigned long long) * (size_t)N, stream);
    simbf_kernel<<<simgrid, TPB, 0, stream>>>(xb, B, inv, rowp, colp, ew, rsd, Er);
    wdeg2_kernel<<<n4grid, TPB, 0, stream>>>(ew, rsd, rowp, base, ptr, deg2, ws_self, N);
    matmulS_kernel<128><<<n4grid, TPB, 0, stream>>>(B, W1, A, N);
    aggfin16_kernel<true, false, true><<<n4grid, TPB, 0, stream>>>(
        A, ew, deg2, rowp, base, ptr, ws_self, b1, B, inv, N);

    // ---------------- layer 2: B[N,16] -> out[N,16], log_softmax ----------------
    hipMemsetAsync(rsd, 0, sizeof(unsigned long long) * (size_t)N, stream);
    sim16_kernel<<<egrid, TPB, 0, stream>>>(B, inv, rowp, colp, ew, rsd, Er);
    wdeg2_kernel<<<n4grid, TPB, 0, stream>>>(ew, rsd, rowp, base, ptr, deg2, ws_self, N);
    matmulS_kernel<16><<<n4grid, TPB, 0, stream>>>(B, W2, A, N);
    aggfin16_kernel<false, true, false><<<n4grid, TPB, 0, stream>>>(
        A, ew, deg2, rowp, base, ptr, ws_self, b2, out, inv, N);
}

// Round 17
// 301.948 us; speedup vs baseline: 1.7187x; 1.0511x over previous
//
#include <hip/hip_runtime.h>

static constexpr int TPB = 256;

// ---- bf16 helpers ----
__device__ __forceinline__ unsigned bf16rne(float x) {
    unsigned u = __float_as_uint(x);
    return (u + 0x7fffu + ((u >> 16) & 1u)) >> 16;
}
__device__ __forceinline__ unsigned pack2(float a, float b) {
    return bf16rne(a) | (bf16rne(b) << 16);
}
__device__ __forceinline__ float dotu(unsigned a, unsigned b) {
    float alo = __uint_as_float(a << 16), ahi = __uint_as_float(a & 0xffff0000u);
    float blo = __uint_as_float(b << 16), bhi = __uint_as_float(b & 0xffff0000u);
    return alo * blo + ahi * bhi;
}
__device__ __forceinline__ float dot4(float4 a, float4 b) {
    return a.x * b.x + a.y * b.y + a.z * b.z + a.w * b.w;
}

// ---- fixed-point packed rs/deg: deg in bits [44..63], rs*2^20 in bits [0..43] ----
__device__ __forceinline__ unsigned long long rsd_pack(float s) {
    return (1ull << 44) | (unsigned long long)__float2uint_rn(s * 1048576.0f);
}
__device__ __forceinline__ float rsd_rs(unsigned long long v) {
    return (float)(v & 0xFFFFFFFFFFFull) * (1.0f / 1048576.0f);
}
__device__ __forceinline__ float rsd_deg(unsigned long long v) {
    return (float)(unsigned)(v >> 44);
}

// ==================== col counting sort -> col-CSR (atomic-free scatter) ====================
__global__ void hist_kernel(const int* __restrict__ col, int* __restrict__ cnt,
                            int* __restrict__ rank, int er) {
    int e = blockIdx.x * TPB + threadIdx.x;
    if (e >= er) return;
    rank[e] = atomicAdd(&cnt[col[e]], 1);
}

__global__ void scan1_kernel(const int* __restrict__ cnt, int* __restrict__ base,
                             int* __restrict__ bsum, int n) {
    __shared__ int s[TPB];
    int g = blockIdx.x * TPB + threadIdx.x;
    int v = (g < n) ? cnt[g] : 0;
    s[threadIdx.x] = v;
    __syncthreads();
    for (int off = 1; off < TPB; off <<= 1) {
        int t = (threadIdx.x >= off) ? s[threadIdx.x - off] : 0;
        __syncthreads();
        s[threadIdx.x] += t;
        __syncthreads();
    }
    if (g < n) base[g] = s[threadIdx.x] - v;
    if (threadIdx.x == TPB - 1) bsum[blockIdx.x] = s[threadIdx.x];
}

__global__ void scan2_kernel(int* __restrict__ bsum, int nb) {
    __shared__ int s[TPB];
    int v = (threadIdx.x < nb) ? bsum[threadIdx.x] : 0;
    s[threadIdx.x] = v;
    __syncthreads();
    for (int off = 1; off < TPB; off <<= 1) {
        int t = (threadIdx.x >= off) ? s[threadIdx.x - off] : 0;
        __syncthreads();
        s[threadIdx.x] += t;
        __syncthreads();
    }
    if (threadIdx.x < nb) bsum[threadIdx.x] = s[threadIdx.x] - v;
}

// base[g] -> global start; ptr[g] -> global END (= start + cnt)
__global__ void scan3_kernel(int* __restrict__ base, int* __restrict__ ptr,
                             const int* __restrict__ bsum, const int* __restrict__ cnt, int n) {
    int g = blockIdx.x * TPB + threadIdx.x;
    if (g >= n) return;
    int b = base[g] + bsum[g >> 8];
    base[g] = b;
    ptr[g] = b + cnt[g];
}

// atomic-free scatter: one 4B scattered store per edge
__global__ void scatter_kernel(const int* __restrict__ row, const int* __restrict__ col,
                               const int* __restrict__ base, const int* __restrict__ rank,
                               int* __restrict__ rowp, int er) {
    int e = blockIdx.x * TPB + threadIdx.x;
    if (e >= er) return;
    rowp[base[col[e]] + rank[e]] = row[e];
}

// coalesced segmented fill of colp from the CSR
__global__ void colfill_kernel(const int* __restrict__ base, const int* __restrict__ endp,
                               int* __restrict__ colp, int n) {
    int gid = blockIdx.x * TPB + threadIdx.x;
    int c = gid >> 2;
    int l = gid & 3;
    if (c >= n) return;
    int e_end = endp[c];
    for (int i = base[c] + l; i < e_end; i += 4) colp[i] = c;
}

// ==================== layer-0: inv norm + normalized bf16 copy (16 lanes/node) ====================
__global__ void norm_kernel(const float* __restrict__ feat, float* __restrict__ inv,
                            unsigned* __restrict__ xb, int n) {
    int gid = blockIdx.x * TPB + threadIdx.x;
    int node = gid >> 4;
    int lane = gid & 15;
    if (node >= n) return;
    const float4* fr = (const float4*)(feat + (size_t)node * 128);
    float4 v0 = fr[lane * 2], v1 = fr[lane * 2 + 1];
    float ss = dot4(v0, v0) + dot4(v1, v1);
#pragma unroll
    for (int off = 8; off > 0; off >>= 1) ss += __shfl_xor(ss, off);
    float iv = (ss > 0.f) ? rsqrtf(ss) : 1.0f;
    if (lane == 0) inv[node] = iv;
    uint4 q;
    q.x = pack2(v0.x * iv, v0.y * iv);
    q.y = pack2(v0.z * iv, v0.w * iv);
    q.z = pack2(v1.x * iv, v1.y * iv);
    q.w = pack2(v1.z * iv, v1.w * iv);
    ((uint4*)xb)[(size_t)node * 16 + lane] = q;
}

// ==================== bf16-screened cosine sim, F=128 (16 lanes/edge, 2 edges/thread) ====================
__global__ void simbf_kernel(const unsigned* __restrict__ xb, const float* __restrict__ feat,
                             const float* __restrict__ inv,
                             const int* __restrict__ rowp, const int* __restrict__ colp,
                             float* __restrict__ sim, unsigned long long* __restrict__ rsd,
                             long long ne) {
    constexpr float MARGIN = 0.02f;
    long long half = (ne + 1) >> 1;
    long long gid = (long long)blockIdx.x * TPB + threadIdx.x;
    long long slot = gid >> 4;
    int lane = (int)(gid & 15);
    if (slot >= half) return;
    long long e0 = slot;
    long long e1 = slot + half;
    bool has1 = (e1 < ne);
    if (!has1) e1 = e0;
    int r0 = rowp[e0], c0 = colp[e0];
    int r1 = rowp[e1], c1 = colp[e1];
    const uint4* X = (const uint4*)xb;
    uint4 a0 = X[(size_t)r0 * 16 + lane];
    uint4 b0 = X[(size_t)c0 * 16 + lane];
    uint4 a1 = X[(size_t)r1 * 16 + lane];
    uint4 b1 = X[(size_t)c1 * 16 + lane];
    float s0 = dotu(a0.x, b0.x) + dotu(a0.y, b0.y) + dotu(a0.z, b0.z) + dotu(a0.w, b0.w);
    float s1 = dotu(a1.x, b1.x) + dotu(a1.y, b1.y) + dotu(a1.z, b1.z) + dotu(a1.w, b1.w);
#pragma unroll
    for (int off = 8; off > 0; off >>= 1) {
        s0 += __shfl_xor(s0, off);
        s1 += __shfl_xor(s1, off);
    }
    if (fabsf(s0 - 0.5f) < MARGIN && r0 != c0) {
        const float4* fa = (const float4*)(feat + (size_t)r0 * 128);
        const float4* fb = (const float4*)(feat + (size_t)c0 * 128);
        float d = dot4(fa[lane * 2], fb[lane * 2]) + dot4(fa[lane * 2 + 1], fb[lane * 2 + 1]);
#pragma unroll
        for (int off = 8; off > 0; off >>= 1) d += __shfl_xor(d, off);
        s0 = d * inv[r0] * inv[c0];
    }
    if (has1 && fabsf(s1 - 0.5f) < MARGIN && r1 != c1) {
        const float4* fa = (const float4*)(feat + (size_t)r1 * 128);
        const float4* fb = (const float4*)(feat + (size_t)c1 * 128);
        float d = dot4(fa[lane * 2], fb[lane * 2]) + dot4(fa[lane * 2 + 1], fb[lane * 2 + 1]);
#pragma unroll
        for (int off = 8; off > 0; off >>= 1) d += __shfl_xor(d, off);
        s1 = d * inv[r1] * inv[c1];
    }
    if (lane == 0) {
        if (s0 < 0.5f || r0 == c0) s0 = 0.f;
        sim[e0] = s0;
        if (s0 > 0.f) atomicAdd(&rsd[r0], rsd_pack(s0));
        if (has1) {
            if (s1 < 0.5f || r1 == c1) s1 = 0.f;
            sim[e1] = s1;
            if (s1 > 0.f) atomicAdd(&rsd[r1], rsd_pack(s1));
        }
    }
}

// ==================== fp32 cosine sim for F=16: one edge/thread, one packed atomic ====================
__global__ void sim16_kernel(const float* __restrict__ feat, const float* __restrict__ inv,
                             const int* __restrict__ rowp, const int* __restrict__ colp,
                             float* __restrict__ sim, unsigned long long* __restrict__ rsd,
                             long long ne) {
    long long e = (long long)blockIdx.x * TPB + threadIdx.x;
    if (e >= ne) return;
    int r = rowp[e], c = colp[e];
    const float4* fa = (const float4*)(feat + (size_t)r * 16);
    const float4* fb = (const float4*)(feat + (size_t)c * 16);
    float4 a0 = fa[0], a1 = fa[1], a2 = fa[2], a3 = fa[3];
    float4 b0 = fb[0], b1 = fb[1], b2 = fb[2], b3 = fb[3];
    float s = dot4(a0, b0) + dot4(a1, b1) + dot4(a2, b2) + dot4(a3, b3);
    s *= inv[r] * inv[c];
    if (s < 0.5f || r == c) s = 0.f;
    sim[e] = s;
    if (s > 0.f) atomicAdd(&rsd[r], rsd_pack(s));
}

// ==================== col-segmented: w=exp(sim/rs[row]); deg2[c]=ws_self+Σw ====================
__global__ void wdeg2_kernel(float* __restrict__ ew, const unsigned long long* __restrict__ rsd,
                             const int* __restrict__ rowp,
                             const int* __restrict__ base, const int* __restrict__ endp,
                             float* __restrict__ deg2, float* __restrict__ ws_self, int n) {
    int gid = blockIdx.x * TPB + threadIdx.x;
    int c = gid >> 2;
    int l = gid & 3;
    if (c >= n) return;
    int s = base[c], e_end = endp[c];
    float sum = 0.f;
    for (int e = s + l; e < e_end; e += 4) {
        float sv = ew[e];
        if (sv > 0.f) {
            float w = __expf(sv / rsd_rs(rsd[rowp[e]]));
            ew[e] = w;
            sum += w;
        }
    }
    sum += __shfl_xor(sum, 1, 4);
    sum += __shfl_xor(sum, 2, 4);
    if (l == 0) {
        float wsf = __expf(1.0f / (rsd_deg(rsd[c]) + 1.0f));
        ws_self[c] = wsf;
        deg2[c] = wsf + sum;
    }
}

// ==================== dense h = feat @ W, 128x128: BM=64 x BN=64 tiles (R13 config) ====================
// 4 nodes x 4 cols per thread, VGPR ~100 natural (no min-waves clause), 17KB LDS, zero spill.
__global__ __launch_bounds__(256) void gemm128_kernel(const float* __restrict__ feat,
                                                      const float* __restrict__ W,
                                                      float* __restrict__ out, int n) {
    constexpr int FIN = 128, FOUT = 128, BK = 32, FPAD = 36;
    __shared__ float Wl[BK * 64];
    __shared__ float Fl[64 * FPAD];
    int tid = threadIdx.x;
    int bm = blockIdx.x >> 1;
    int half = blockIdx.x & 1;
    int base = bm * 64;
    int j4 = tid & 15;
    int sub = tid >> 4;
    float4 acc[4];
#pragma unroll
    for (int s = 0; s < 4; ++s) acc[s] = make_float4(0.f, 0.f, 0.f, 0.f);

    for (int t = 0; t < FIN / BK; ++t) {
        int k0 = t * BK;
        if (t > 0) __syncthreads();
#pragma unroll
        for (int i = 0; i < 2; ++i) {
            int idx = tid + 256 * i;
            int r = idx >> 4, c4 = idx & 15;
            *(float4*)&Wl[r * 64 + c4 * 4] =
                *(const float4*)(W + (size_t)(k0 + r) * FOUT + half * 64 + c4 * 4);
        }
#pragma unroll
        for (int i = 0; i < 2; ++i) {
            int idx = tid + 256 * i;
            int r = idx >> 3, c4 = idx & 7;
            int node = base + r;
            float4 v = make_float4(0.f, 0.f, 0.f, 0.f);
            if (node < n) v = *(const float4*)(feat + (size_t)node * FIN + k0 + c4 * 4);
            *(float4*)&Fl[r * FPAD + c4 * 4] = v;
        }
        __syncthreads();
#pragma unroll
        for (int k = 0; k < BK; k += 4) {
            float4 w0 = *(const float4*)&Wl[(k + 0) * 64 + j4 * 4];
            float4 w1 = *(const float4*)&Wl[(k + 1) * 64 + j4 * 4];
            float4 w2 = *(const float4*)&Wl[(k + 2) * 64 + j4 * 4];
            float4 w3 = *(const float4*)&Wl[(k + 3) * 64 + j4 * 4];
#pragma unroll
            for (int s = 0; s < 4; ++s) {
                float4 f = *(const float4*)&Fl[(sub + s * 16) * FPAD + k];
                acc[s].x += f.x * w0.x + f.y * w1.x + f.z * w2.x + f.w * w3.x;
                acc[s].y += f.x * w0.y + f.y * w1.y + f.z * w2.y + f.w * w3.y;
                acc[s].z += f.x * w0.z + f.y * w1.z + f.z * w2.z + f.w * w3.z;
                acc[s].w += f.x * w0.w + f.y * w1.w + f.z * w2.w + f.w * w3.w;
            }
        }
    }
#pragma unroll
    for (int s = 0; s < 4; ++s) {
        int node = base + sub + s * 16;
        if (node < n)
            *(float4*)(out + (size_t)node * FOUT + half * 64 + j4 * 4) = acc[s];
    }
}

// ==================== h = feat @ W for FOUT=16 (4 lanes per node, float4) ====================
template<int FIN>
__global__ void matmulS_kernel(const float* __restrict__ feat, const float* __restrict__ W,
                               float* __restrict__ out, int n) {
    __shared__ float4 Wl[FIN * 4];
    for (int i = threadIdx.x; i < FIN * 4; i += TPB) Wl[i] = ((const float4*)W)[i];
    __syncthreads();
    int gid = blockIdx.x * TPB + threadIdx.x;
    int node = gid >> 2;
    int j4 = gid & 3;
    if (node >= n) return;
    const float4* fr = (const float4*)(feat + (size_t)node * FIN);
    float4 acc = make_float4(0.f, 0.f, 0.f, 0.f);
#pragma unroll
    for (int k4 = 0; k4 < FIN / 4; ++k4) {
        float4 f = fr[k4];
        float4 w0 = Wl[(4 * k4 + 0) * 4 + j4];
        float4 w1 = Wl[(4 * k4 + 1) * 4 + j4];
        float4 w2 = Wl[(4 * k4 + 2) * 4 + j4];
        float4 w3 = Wl[(4 * k4 + 3) * 4 + j4];
        acc.x += f.x * w0.x + f.y * w1.x + f.z * w2.x + f.w * w3.x;
        acc.y += f.x * w0.y + f.y * w1.y + f.z * w2.y + f.w * w3.y;
        acc.z += f.x * w0.z + f.y * w1.z + f.z * w2.z + f.w * w3.z;
        acc.w += f.x * w0.w + f.y * w1.w + f.z * w2.w + f.w * w3.w;
    }
    *((float4*)(out + (size_t)node * 16) + j4) = acc;
}

// ==================== fused segmented aggregate + finalize, F=128 (32 lanes/col) ====================
template<bool RELU>
__global__ void aggfin128_kernel(const float* __restrict__ h, const float* __restrict__ ew,
                                 const float* __restrict__ deg2, const int* __restrict__ rowp,
                                 const int* __restrict__ base, const int* __restrict__ endp,
                                 const float* __restrict__ ws_self, const float* __restrict__ b,
                                 float* __restrict__ outb, float* __restrict__ inv,
                                 unsigned* __restrict__ xb, int n) {
    int gid = blockIdx.x * TPB + threadIdx.x;
    int c = gid >> 5;
    int j4 = gid & 31;
    if (c >= n) return;
    int s = base[c], e_end = endp[c];
    float d2c = deg2[c];
    float dc = rsqrtf(d2c);
    float4 acc = make_float4(0.f, 0.f, 0.f, 0.f);
    for (int e = s; e < e_end; ++e) {
        float we = ew[e];
        if (we == 0.f) continue;
        int r = rowp[e];
        float nw = rsqrtf(deg2[r]) * we * dc;
        float4 hv = *((const float4*)(h + (size_t)r * 128) + j4);
        acc.x += nw * hv.x; acc.y += nw * hv.y; acc.z += nw * hv.z; acc.w += nw * hv.w;
    }
    float nws = ws_self[c] / d2c;
    float4 hv = *((const float4*)(h + (size_t)c * 128) + j4);
    float4 bv = ((const float4*)b)[j4];
    float4 o;
    o.x = acc.x + nws * hv.x + bv.x;
    o.y = acc.y + nws * hv.y + bv.y;
    o.z = acc.z + nws * hv.z + bv.z;
    o.w = acc.w + nws * hv.w + bv.w;
    if (RELU) {
        o.x = fmaxf(o.x, 0.f); o.y = fmaxf(o.y, 0.f);
        o.z = fmaxf(o.z, 0.f); o.w = fmaxf(o.w, 0.f);
    }
    *((float4*)(outb + (size_t)c * 128) + j4) = o;
    float ss = o.x * o.x + o.y * o.y + o.z * o.z + o.w * o.w;
#pragma unroll
    for (int off = 16; off > 0; off >>= 1)
        ss += __shfl_xor(ss, off, 32);
    float iv = (ss > 0.f) ? rsqrtf(ss) : 1.0f;
    if (j4 == 0) inv[c] = iv;
    uint2 p;
    p.x = pack2(o.x * iv, o.y * iv);
    p.y = pack2(o.z * iv, o.w * iv);
    ((uint2*)xb)[(size_t)c * 32 + j4] = p;
}

// ==================== fused segmented aggregate + finalize, F=16 (4 lanes/col) ====================
template<bool RELU, bool LOGSM, bool WINV>
__global__ void aggfin16_kernel(const float* __restrict__ h, const float* __restrict__ ew,
                                const float* __restrict__ deg2, const int* __restrict__ rowp,
                                const int* __restrict__ base, const int* __restrict__ endp,
                                const float* __restrict__ ws_self, const float* __restrict__ b,
                                float* __restrict__ out, float* __restrict__ inv, int n) {
    int gid = blockIdx.x * TPB + threadIdx.x;
    int c = gid >> 2;
    int l = gid & 3;
    if (c >= n) return;
    int s = base[c], e_end = endp[c];
    float d2c = deg2[c];
    float dc = rsqrtf(d2c);
    float4 acc = make_float4(0.f, 0.f, 0.f, 0.f);
    for (int e = s; e < e_end; ++e) {
        float we = ew[e];
        if (we == 0.f) continue;
        int r = rowp[e];
        float nw = rsqrtf(deg2[r]) * we * dc;
        float4 hv = *((const float4*)(h + (size_t)r * 16) + l);
        acc.x += nw * hv.x; acc.y += nw * hv.y; acc.z += nw * hv.z; acc.w += nw * hv.w;
    }
    float nws = ws_self[c] / d2c;
    float4 hv = *((const float4*)(h + (size_t)c * 16) + l);
    float4 bv = ((const float4*)b)[l];
    float4 v;
    v.x = acc.x + nws * hv.x + bv.x;
    v.y = acc.y + nws * hv.y + bv.y;
    v.z = acc.z + nws * hv.z + bv.z;
    v.w = acc.w + nws * hv.w + bv.w;
    if (RELU) {
        v.x = fmaxf(v.x, 0.f); v.y = fmaxf(v.y, 0.f);
        v.z = fmaxf(v.z, 0.f); v.w = fmaxf(v.w, 0.f);
    }
    if (WINV) {
        float ss = v.x * v.x + v.y * v.y + v.z * v.z + v.w * v.w;
        ss += __shfl_xor(ss, 1, 4);
        ss += __shfl_xor(ss, 2, 4);
        if (l == 0) inv[c] = (ss > 0.f) ? rsqrtf(ss) : 1.0f;
    }
    if (LOGSM) {
        float m = fmaxf(fmaxf(v.x, v.y), fmaxf(v.z, v.w));
        m = fmaxf(m, __shfl_xor(m, 1, 4));
        m = fmaxf(m, __shfl_xor(m, 2, 4));
        float sm = expf(v.x - m) + expf(v.y - m) + expf(v.z - m) + expf(v.w - m);
        sm += __shfl_xor(sm, 1, 4);
        sm += __shfl_xor(sm, 2, 4);
        float ls = m + logf(sm);
        v.x -= ls; v.y -= ls; v.z -= ls; v.w -= ls;
    }
    *((float4*)(out + (size_t)c * 16) + l) = v;
}

extern "C" void kernel_launch(void* const* d_in, const int* in_sizes, int n_in,
                              void* d_out, int out_size, void* d_ws, size_t ws_size,
                              hipStream_t stream) {
    const float* x  = (const float*)d_in[0];
    const int*   row = (const int*)d_in[1];
    const int*   col = (const int*)d_in[2];
    const float* W0 = (const float*)d_in[3];
    const float* b0 = (const float*)d_in[4];
    const float* W1 = (const float*)d_in[5];
    const float* b1 = (const float*)d_in[6];
    const float* W2 = (const float*)d_in[7];
    const float* b2 = (const float*)d_in[8];

    const int NFEAT = 128, NHID = 128;
    int N = in_sizes[0] / NFEAT;            // 50000
    long long E = in_sizes[1];              // 850000 (tail N are self-loops)
    long long Er = E - N;                   // 800000 random edges
    int er = (int)Er;

    float* ws = (float*)d_ws;
    float* A       = ws;                          // [N,128] h
    float* B       = A + (size_t)N * NHID;        // [N,128] feat buffer
    float* ew      = B + (size_t)N * NHID;        // [Er] sim -> w (col-sorted order)
    unsigned long long* rsd = (unsigned long long*)(ew + Er);   // [N] packed rs|deg
    float* inv     = (float*)(rsd + N);           // [N]
    float* deg2    = inv + N;                     // [N]
    float* ws_self = deg2 + N;                    // [N]
    int* cnt    = (int*)(ws_self + N);            // [N]
    int* base   = cnt + N;                        // [N] col-CSR starts
    int* ptr    = base + N;                       // [N] col-CSR ends
    int* bsum   = ptr + N;                        // [256]
    int* rank   = bsum + 256;                     // [Er] within-col rank
    int* rowp   = rank + Er;                      // [Er]
    int* colp   = rowp + Er;                      // [Er]
    unsigned* xb = (unsigned*)(colp + Er);        // [N*64] bf16x2 packed
    float* out  = (float*)d_out;                  // [N,16]

    int nb = (N + TPB - 1) / TPB;
    unsigned egrid = (unsigned)((er + TPB - 1) / TPB);
    unsigned n4grid = (unsigned)(((long long)N * 4 + TPB - 1) / TPB);

    // ---- col sort -> col-CSR; scatter has NO atomics (rank precomputed in hist) ----
    hipMemsetAsync(cnt, 0, sizeof(int) * (size_t)N, stream);
    hist_kernel<<<egrid, TPB, 0, stream>>>(col, cnt, rank, er);
    scan1_kernel<<<nb, TPB, 0, stream>>>(cnt, base, bsum, N);
    scan2_kernel<<<1, TPB, 0, stream>>>(bsum, nb);
    scan3_kernel<<<nb, TPB, 0, stream>>>(base, ptr, bsum, cnt, N);
    scatter_kernel<<<egrid, TPB, 0, stream>>>(row, col, base, rank, rowp, er);
    colfill_kernel<<<n4grid, TPB, 0, stream>>>(base, ptr, colp, N);

    // layer-0 norms + bf16 copy
    norm_kernel<<<(unsigned)(((long long)N * 16 + TPB - 1) / TPB), TPB, 0, stream>>>(x, inv, xb, N);

    long long half = (Er + 1) >> 1;
    unsigned simgrid = (unsigned)((half * 16 + TPB - 1) / TPB);

    // ---------------- layer 0: x[N,128] -> B[N,128], relu ----------------
    hipMemsetAsync(rsd, 0, sizeof(unsigned long long) * (size_t)N, stream);
    simbf_kernel<<<simgrid, TPB, 0, stream>>>(xb, x, inv, rowp, colp, ew, rsd, Er);
    wdeg2_kernel<<<n4grid, TPB, 0, stream>>>(ew, rsd, rowp, base, ptr, deg2, ws_self, N);
    gemm128_kernel<<<(unsigned)(2 * ((N + 63) / 64)), 256, 0, stream>>>(x, W0, A, N);
    aggfin128_kernel<true><<<(unsigned)(((long long)N * 32 + TPB - 1) / TPB), TPB, 0, stream>>>(
        A, ew, deg2, rowp, base, ptr, ws_self, b0, B, inv, xb, N);

    // ---------------- layer 1: B[N,128] -> B[N,16], relu ----------------
    hipMemsetAsync(rsd, 0, sizeof(unsigned long long) * (size_t)N, stream);
    simbf_kernel<<<simgrid, TPB, 0, stream>>>(xb, B, inv, rowp, colp, ew, rsd, Er);
    wdeg2_kernel<<<n4grid, TPB, 0, stream>>>(ew, rsd, rowp, base, ptr, deg2, ws_self, N);
    matmulS_kernel<128><<<n4grid, TPB, 0, stream>>>(B, W1, A, N);
    aggfin16_kernel<true, false, true><<<n4grid, TPB, 0, stream>>>(
        A, ew, deg2, rowp, base, ptr, ws_self, b1, B, inv, N);

    // ---------------- layer 2: B[N,16] -> out[N,16], log_softmax ----------------
    hipMemsetAsync(rsd, 0, sizeof(unsigned long long) * (size_t)N, stream);
    sim16_kernel<<<egrid, TPB, 0, stream>>>(B, inv, rowp, colp, ew, rsd, Er);
    wdeg2_kernel<<<n4grid, TPB, 0, stream>>>(ew, rsd, rowp, base, ptr, deg2, ws_self, N);
    matmulS_kernel<16><<<n4grid, TPB, 0, stream>>>(B, W2, A, N);
    aggfin16_kernel<false, true, false><<<n4grid, TPB, 0, stream>>>(
        A, ew, deg2, rowp, base, ptr, ws_self, b2, out, inv, N);
}